// Round 1
// baseline (924.184 us; speedup 1.0000x reference)
//
#include <hip/hip_runtime.h>

// ---------------------------------------------------------------------------
// GraphTrajSimEncoder on MI355X — round 7.
// R6 changes (from 783 µs baseline):
//  - k_agg v3: 2 edges per wave-slot (dwordx4 gathers, 16B/lane, half the VMEM
//    instrs), packed f32 FMA (v_pk_fma_f32 via float2), self-loop folded into
//    CSR as a record (no prologue self-row/dinv loads), cross-half shfl combine
//  - k_scan2 (single-block serial scan, latency-bound on 2/256 CUs) replaced
//    with 3-phase multi-block scan (scanA local / scanB block-sums / scanC add)
// ---------------------------------------------------------------------------

using bf16x8  = __attribute__((ext_vector_type(8))) __bf16;
using floatx4 = __attribute__((ext_vector_type(4))) float;
using f32x2   = __attribute__((ext_vector_type(2))) float;

__device__ __forceinline__ float b2f(unsigned short b) {
    return __uint_as_float(((unsigned)b) << 16);
}
__device__ __forceinline__ unsigned short f2b(float f) {
    unsigned u = __float_as_uint(f);
    return (unsigned short)((u + 0x7FFFu + ((u >> 16) & 1u)) >> 16);
}
__device__ __forceinline__ unsigned short f2h(float f) {
    _Float16 h = (_Float16)f;
    return __builtin_bit_cast(unsigned short, h);
}
__device__ __forceinline__ float h2f(unsigned short u) {
    return (float)__builtin_bit_cast(_Float16, u);
}

// ---------------- graph preprocessing ----------------

__global__ void k_cnt2(const int* __restrict__ col0, const int* __restrict__ col1,
                       int E, int* __restrict__ cnt0, int* __restrict__ cnt1) {
    int e = blockIdx.x * 256 + threadIdx.x;
    const int* col = blockIdx.y ? col1 : col0;
    int* cnt = blockIdx.y ? cnt1 : cnt0;
    if (e < E) atomicAdd(&cnt[col[e]], 1);
}

// 3-phase scan of padded counts. Pad = cnt + 1 (self record) rounded up to 8.
// Phase A: per-block (1024 elems) inclusive scan -> off[i+1] (local), block sum.
__global__ __launch_bounds__(1024) void k_scanA(
    const int* __restrict__ cnt0, const int* __restrict__ cnt1,
    int* __restrict__ off0, int* __restrict__ off1,
    int* __restrict__ bs0, int* __restrict__ bs1, int n) {
    const int* cnt = blockIdx.y ? cnt1 : cnt0;
    int* off = blockIdx.y ? off1 : off0;
    int* bs  = blockIdx.y ? bs1 : bs0;
    __shared__ int wsum[16];
    __shared__ int wpre[16];
    const int t = threadIdx.x;
    const int lane = t & 63;
    const int w = t >> 6;
    const int i = blockIdx.x * 1024 + t;
    int v = (i < n) ? ((cnt[i] + 8) & ~7) : 0;   // cnt + self, padded to x8
    #pragma unroll
    for (int d = 1; d < 64; d <<= 1) {
        int u = __shfl_up(v, d, 64);
        if (lane >= d) v += u;
    }
    if (lane == 63) wsum[w] = v;
    __syncthreads();
    if (t < 16) {
        int s2 = wsum[t];
        #pragma unroll
        for (int d = 1; d < 16; d <<= 1) {
            int u = __shfl_up(s2, d, 16);
            if (t >= d) s2 += u;
        }
        wpre[t] = s2;
    }
    __syncthreads();
    int incl = v + (w > 0 ? wpre[w - 1] : 0);
    if (i < n) off[i + 1] = incl;
    if (t == 1023) bs[blockIdx.x] = incl;
}

// Phase B: one wave scans the (<=64) block sums -> exclusive prefixes in place.
__global__ void k_scanB(int* __restrict__ bs0, int* __restrict__ bs1, int nb) {
    int* bs = blockIdx.y ? bs1 : bs0;
    const int t = threadIdx.x;       // 64 threads
    int v = (t < nb) ? bs[t] : 0;
    int orig = v;
    #pragma unroll
    for (int d = 1; d < 64; d <<= 1) {
        int u = __shfl_up(v, d, 64);
        if (t >= d) v += u;
    }
    if (t < nb) bs[t] = v - orig;    // exclusive
}

// Phase C: add block prefix; set off[0]=0.
__global__ __launch_bounds__(1024) void k_scanC(
    const int* __restrict__ bs0, const int* __restrict__ bs1,
    int* __restrict__ off0, int* __restrict__ off1, int n) {
    int* off = blockIdx.y ? off1 : off0;
    const int* bs = blockIdx.y ? bs1 : bs0;
    const int i = blockIdx.x * 1024 + threadIdx.x;
    if (i == 0) off[0] = 0;
    if (i < n && blockIdx.x > 0) off[i + 1] += bs[blockIdx.x];
}

// dinv = rsqrt(REAL deg + 1), cur = off  — grid (gN,2)
__global__ void k_prep(const int* __restrict__ cnt0, const int* __restrict__ cnt1,
                       const int* __restrict__ off0, const int* __restrict__ off1,
                       float* __restrict__ dinv0, float* __restrict__ dinv1,
                       int* __restrict__ cur0, int* __restrict__ cur1, int n) {
    int i = blockIdx.x * 256 + threadIdx.x;
    if (i >= n) return;
    const int* cnt = blockIdx.y ? cnt1 : cnt0;
    const int* off = blockIdx.y ? off1 : off0;
    float* dinv = blockIdx.y ? dinv1 : dinv0;
    int* cur = blockIdx.y ? cur1 : cur0;
    dinv[i] = rsqrtf((float)(cnt[i] + 1));
    cur[i] = off[i];
}

// CSR fill: 8B record per edge = (src:u32, (fp16 w1)<<16 | fp16 w2).
__global__ void k_fill2(const int* __restrict__ ei0, const float* __restrict__ ea0,
                        const int* __restrict__ ei1, const float* __restrict__ ea1,
                        int E, const float* __restrict__ dinv0,
                        const float* __restrict__ dinv1,
                        int* __restrict__ cur0, int* __restrict__ cur1,
                        uint2* __restrict__ rec0, uint2* __restrict__ rec1) {
    int e = blockIdx.x * 256 + threadIdx.x;
    if (e >= E) return;
    const int* ei = blockIdx.y ? ei1 : ei0;
    const float* ea = blockIdx.y ? ea1 : ea0;
    const float* dinv = blockIdx.y ? dinv1 : dinv0;
    int* cur = blockIdx.y ? cur1 : cur0;
    uint2* rec = blockIdx.y ? rec1 : rec0;
    int r = ei[e];          // source
    int c = ei[E + e];      // target
    float a = ea[e];
    float w2 = (a > 0.0f) ? fminf(rsqrtf(a), 1.0f) : 0.0f;
    float w1 = dinv[r] * dinv[c];
    int p = atomicAdd(&cur[c], 1);
    rec[p] = make_uint2((unsigned)r,
                        ((unsigned)f2h(w1) << 16) | (unsigned)f2h(w2));
}

// self-loop record (w1 = dinv^2, w2 = 1.0) + zero-pad tail — grid (gN,2)
__global__ void k_pad(const int* __restrict__ cnt0, const int* __restrict__ cnt1,
                      const int* __restrict__ off0, const int* __restrict__ off1,
                      const float* __restrict__ dinv0, const float* __restrict__ dinv1,
                      uint2* __restrict__ rec0, uint2* __restrict__ rec1, int n) {
    int i = blockIdx.x * 256 + threadIdx.x;
    if (i >= n) return;
    const int* cnt = blockIdx.y ? cnt1 : cnt0;
    const int* off = blockIdx.y ? off1 : off0;
    const float* dinv = blockIdx.y ? dinv1 : dinv0;
    uint2* rec = blockIdx.y ? rec1 : rec0;
    int p = off[i] + cnt[i], pe = off[i + 1];
    float di = dinv[i];
    rec[p++] = make_uint2((unsigned)i,
                          ((unsigned)f2h(di * di) << 16) | 0x3C00u);  // w2 = 1.0
    for (; p < pe; ++p) rec[p] = make_uint2(0u, 0u);
}

// ---------------- dtype conversions ----------------

// xc[i][k] (bf16, K padded to KP): k<F -> x, k<KC -> d2an, else 0  (row-major)
__global__ void k_xc(const float* __restrict__ x, const float* __restrict__ pe,
                     unsigned short* __restrict__ xc, int n, int F, int PEd,
                     int KC, int KP) {
    int idx = blockIdx.x * 256 + threadIdx.x;
    if (idx >= n * KP) return;
    int i = idx / KP, k = idx - i * KP;
    float v = 0.0f;
    if (k < F)        v = x[(size_t)i * F + k];
    else if (k < KC)  v = pe[(size_t)i * PEd + (k - F)];
    xc[idx] = f2b(v);
}

// weight conversions (row-major K):
//   seg 0/1: Wn [F][KC] f32 -> [F][KP] bf16 zero-padded
//   seg 2..5: [Wa|Wb] pairs -> [F][512] bf16 plain concat
__global__ void k_wall(const float* __restrict__ Wn1, const float* __restrict__ Wn2,
                       const float* __restrict__ W11, const float* __restrict__ W12,
                       const float* __restrict__ W21, const float* __restrict__ W22,
                       const float* __restrict__ W31, const float* __restrict__ W32,
                       const float* __restrict__ W41, const float* __restrict__ W42,
                       unsigned short* __restrict__ wn0c, unsigned short* __restrict__ wn1c,
                       unsigned short* __restrict__ wc0, unsigned short* __restrict__ wc1,
                       unsigned short* __restrict__ wc2, unsigned short* __restrict__ wc3,
                       int F, int KC, int KP) {
    int idx = blockIdx.x * 256 + threadIdx.x;
    int npad = F * KP;
    if (idx < 2 * npad) {
        const float* W = (idx < npad) ? Wn1 : Wn2;
        unsigned short* Wc = (idx < npad) ? wn0c : wn1c;
        int t = (idx < npad) ? idx : idx - npad;
        int o = t / KP, k = t - o * KP;
        Wc[t] = f2b(k < KC ? W[(size_t)o * KC + k] : 0.0f);
        return;
    }
    int t = idx - 2 * npad;
    int seg = F * 512;
    if (t >= 4 * seg) return;
    int which = t / seg;
    int r = t - which * seg;
    const float* Wa = (which == 0) ? W11 : (which == 1) ? W21 : (which == 2) ? W31 : W41;
    const float* Wb = (which == 0) ? W12 : (which == 1) ? W22 : (which == 2) ? W32 : W42;
    unsigned short* Wc = (which == 0) ? wc0 : (which == 1) ? wc1 : (which == 2) ? wc2 : wc3;
    int o = r >> 9, k = r & 511;
    float v = (k < 256) ? Wa[(size_t)o * 256 + k] : Wb[(size_t)o * 256 + (k - 256)];
    Wc[r] = f2b(v);
}

// ---------------- CSR gather-aggregation v3 ----------------
// One wave per node. Lanes 0-31 process even-indexed records, 32-63 odd ones:
// each gather is a dwordx4 (16B/lane, 8 feats) covering 2 edges per instr.
// Self loop is an ordinary CSR record; zero-pad records are (row0, w=0).
// Epilogue: cross-half shfl_xor(32) combine; lanes<32 write a1, lanes>=32 a2.
// Output A[i] = [a1(256) | a2(256)] bf16.
__global__ __launch_bounds__(256) void k_agg(
    const unsigned short* __restrict__ X0, const unsigned short* __restrict__ X1,
    const int* __restrict__ off0, const int* __restrict__ off1,
    const uint2* __restrict__ rec0, const uint2* __restrict__ rec1,
    unsigned short* __restrict__ A0, unsigned short* __restrict__ A1, int n) {
    const int s = blockIdx.y;
    const char* Xb = (const char*)(s ? X1 : X0);
    const int* off = s ? off1 : off0;
    const uint2* rec = s ? rec1 : rec0;
    unsigned short* A = s ? A1 : A0;

    const int gw = (blockIdx.x * 256 + threadIdx.x) >> 6;
    const int lane = threadIdx.x & 63;
    if (gw >= n) return;

    const int e0 = __builtin_amdgcn_readfirstlane(off[gw]);
    const int e1 = __builtin_amdgcn_readfirstlane(off[gw + 1]);
    const bool hi = lane >= 32;
    const unsigned loff = (unsigned)(lane & 31) << 4;   // 16B chunk within row

    f32x2 acc1[4], acc2[4];
    #pragma unroll
    for (int d = 0; d < 4; ++d) {
        acc1[d] = (f32x2){0.f, 0.f};
        acc2[d] = (f32x2){0.f, 0.f};
    }

    const uint4* recq = (const uint4*)(rec + e0);   // 1 uint4 = 2 records
    const int nit = (e1 - e0) >> 3;                 // 8 records / iter
    for (int it = 0; it < nit; ++it) {
        uint4 q[4];
        #pragma unroll
        for (int k = 0; k < 4; ++k) q[k] = recq[it * 4 + k];   // broadcast loads
        uint4 g[4];
        unsigned wsel[4];
        #pragma unroll
        for (int k = 0; k < 4; ++k) {
            unsigned srcsel = hi ? q[k].z : q[k].x;
            wsel[k] = hi ? q[k].w : q[k].y;
            g[k] = *(const uint4*)(Xb + (((srcsel << 9) | loff)));
        }
        #pragma unroll
        for (int k = 0; k < 4; ++k) {
            float w1 = h2f((unsigned short)(wsel[k] >> 16));
            float w2 = h2f((unsigned short)(wsel[k] & 0xFFFFu));
            f32x2 w1v = {w1, w1};
            f32x2 w2v = {w2, w2};
            const unsigned* gd = (const unsigned*)&g[k];
            #pragma unroll
            for (int d = 0; d < 4; ++d) {
                f32x2 v;
                v.x = __uint_as_float(gd[d] << 16);
                v.y = __uint_as_float(gd[d] & 0xFFFF0000u);
                acc1[d] = __builtin_elementwise_fma(w1v, v, acc1[d]);
                acc2[d] = __builtin_elementwise_fma(w2v, v, acc2[d]);
            }
        }
    }

    // combine halves (lane L and L^32 hold the same 8 feats over disjoint edges)
    float o1[8], o2[8];
    #pragma unroll
    for (int d = 0; d < 4; ++d) {
        o1[2 * d]     = acc1[d].x + __shfl_xor(acc1[d].x, 32);
        o1[2 * d + 1] = acc1[d].y + __shfl_xor(acc1[d].y, 32);
        o2[2 * d]     = acc2[d].x + __shfl_xor(acc2[d].x, 32);
        o2[2 * d + 1] = acc2[d].y + __shfl_xor(acc2[d].y, 32);
    }
    // static-index per-element select (avoid runtime-indexed array -> scratch)
    float s0 = hi ? o2[0] : o1[0];
    float s1 = hi ? o2[1] : o1[1];
    float s2 = hi ? o2[2] : o1[2];
    float s3 = hi ? o2[3] : o1[3];
    float s4 = hi ? o2[4] : o1[4];
    float s5 = hi ? o2[5] : o1[5];
    float s6 = hi ? o2[6] : o1[6];
    float s7 = hi ? o2[7] : o1[7];
    uint4 o;
    o.x = (unsigned)f2b(s0) | ((unsigned)f2b(s1) << 16);
    o.y = (unsigned)f2b(s2) | ((unsigned)f2b(s3) << 16);
    o.z = (unsigned)f2b(s4) | ((unsigned)f2b(s5) << 16);
    o.w = (unsigned)f2b(s6) | ((unsigned)f2b(s7) << 16);
    *(uint4*)(A + (size_t)gw * 512 + (hi ? 256 : 0) + ((lane & 31) << 3)) = o;
}

// ---------------- bf16 MFMA GEMM kernels ----------------
#define GLL(g, l) \
    __builtin_amdgcn_global_load_lds((__attribute__((address_space(1))) void*)(g), \
                                     (__attribute__((address_space(3))) void*)(l), 16, 0, 0)

// node-transform GEMM: C[M][Nc] = A[M][K] @ B[Nc][K]^T, bf16 out, z selects B/out.
__global__ __launch_bounds__(256) void gemm_bt(
    const unsigned short* __restrict__ A,
    const unsigned short* __restrict__ B0, const unsigned short* __restrict__ B1,
    int M, int K, int Nc,
    unsigned short* __restrict__ outH0, unsigned short* __restrict__ outH1) {
    const unsigned short* B = blockIdx.z ? B1 : B0;
    unsigned short* outH = blockIdx.z ? outH1 : outH0;

    __shared__ __align__(16) unsigned short sA[128 * 32];
    __shared__ __align__(16) unsigned short sB[128 * 32];
    const int tid = threadIdx.x;
    const int lane = tid & 63;
    const int wave = tid >> 6;
    const int bm = blockIdx.x * 128;
    const int bn = blockIdx.y * 128;

    const int r0 = wave * 32 + (lane >> 2);
    const int kcol = (lane & 3) * 8;
    const int ga0 = min(bm + r0, M - 1);
    const int ga1 = min(bm + r0 + 16, M - 1);
    const int gb0 = min(bn + r0, Nc - 1);
    const int gb1 = min(bn + r0 + 16, Nc - 1);
    const unsigned short* pa0 = A + (size_t)ga0 * K + kcol;
    const unsigned short* pa1 = A + (size_t)ga1 * K + kcol;
    const unsigned short* pb0 = B + (size_t)gb0 * K + kcol;
    const unsigned short* pb1 = B + (size_t)gb1 * K + kcol;
    unsigned short* la0 = &sA[wave * 1024];
    unsigned short* la1 = &sA[wave * 1024 + 512];
    unsigned short* lb0 = &sB[wave * 1024];
    unsigned short* lb1 = &sB[wave * 1024 + 512];

    floatx4 acc[4][4];
    #pragma unroll
    for (int i = 0; i < 4; i++)
        #pragma unroll
        for (int j = 0; j < 4; j++) acc[i][j] = (floatx4){0.f, 0.f, 0.f, 0.f};

    const int mbase = (wave & 1) * 64 + (lane & 15);
    const int nbase = (wave >> 1) * 64 + (lane & 15);
    const int koff = (lane >> 4) * 8;

    for (int kk = 0; kk < K; kk += 32) {
        GLL(pa0 + kk, la0);
        GLL(pa1 + kk, la1);
        GLL(pb0 + kk, lb0);
        GLL(pb1 + kk, lb1);
        __syncthreads();
        bf16x8 af[4], bf[4];
        #pragma unroll
        for (int mi = 0; mi < 4; mi++)
            af[mi] = *(const bf16x8*)&sA[(mbase + mi * 16) * 32 + koff];
        #pragma unroll
        for (int ni = 0; ni < 4; ni++)
            bf[ni] = *(const bf16x8*)&sB[(nbase + ni * 16) * 32 + koff];
        #pragma unroll
        for (int mi = 0; mi < 4; mi++)
            #pragma unroll
            for (int ni = 0; ni < 4; ni++)
                acc[mi][ni] = __builtin_amdgcn_mfma_f32_16x16x32_bf16(
                    af[mi], bf[ni], acc[mi][ni], 0, 0, 0);
        __syncthreads();
    }

    const int crow = bm + (wave & 1) * 64 + (lane >> 4) * 4;
    const int ccol = bn + (wave >> 1) * 64 + (lane & 15);
    #pragma unroll
    for (int mi = 0; mi < 4; mi++)
        #pragma unroll
        for (int ni = 0; ni < 4; ni++)
            #pragma unroll
            for (int r = 0; r < 4; r++) {
                int row = crow + mi * 16 + r;
                if (row >= M) continue;
                int col = ccol + ni * 16;
                outH[(size_t)row * Nc + col] = f2b(acc[mi][ni][r]);
            }
}

// dual GEMM: C = 0.5*relu(A0@B0^T) + 0.5*relu(A1@B1^T); out f32 or bf16.
__global__ __launch_bounds__(256) void gemm_dual(
    const unsigned short* __restrict__ A0, const unsigned short* __restrict__ B0,
    const unsigned short* __restrict__ A1, const unsigned short* __restrict__ B1,
    int M, int K, int Nc,
    float* __restrict__ outF, unsigned short* __restrict__ outH, float alpha) {
    __shared__ __align__(16) unsigned short sA[128 * 32];
    __shared__ __align__(16) unsigned short sB[128 * 32];
    const int tid = threadIdx.x;
    const int lane = tid & 63;
    const int wave = tid >> 6;
    const int bm = blockIdx.x * 128;
    const int bn = blockIdx.y * 128;

    const int r0 = wave * 32 + (lane >> 2);
    const int kcol = (lane & 3) * 8;
    const int ga0 = min(bm + r0, M - 1);
    const int ga1 = min(bm + r0 + 16, M - 1);
    const int gb0 = min(bn + r0, Nc - 1);
    const int gb1 = min(bn + r0 + 16, Nc - 1);
    unsigned short* la0 = &sA[wave * 1024];
    unsigned short* la1 = &sA[wave * 1024 + 512];
    unsigned short* lb0 = &sB[wave * 1024];
    unsigned short* lb1 = &sB[wave * 1024 + 512];

    const int mbase = (wave & 1) * 64 + (lane & 15);
    const int nbase = (wave >> 1) * 64 + (lane & 15);
    const int koff = (lane >> 4) * 8;

    floatx4 acc[4][4], res[4][4];

    #pragma unroll
    for (int pass = 0; pass < 2; pass++) {
        const unsigned short* A = pass ? A1 : A0;
        const unsigned short* B = pass ? B1 : B0;
        const unsigned short* pa0 = A + (size_t)ga0 * K + kcol;
        const unsigned short* pa1 = A + (size_t)ga1 * K + kcol;
        const unsigned short* pb0 = B + (size_t)gb0 * K + kcol;
        const unsigned short* pb1 = B + (size_t)gb1 * K + kcol;
        #pragma unroll
        for (int i = 0; i < 4; i++)
            #pragma unroll
            for (int j = 0; j < 4; j++) acc[i][j] = (floatx4){0.f, 0.f, 0.f, 0.f};

        for (int kk = 0; kk < K; kk += 32) {
            GLL(pa0 + kk, la0);
            GLL(pa1 + kk, la1);
            GLL(pb0 + kk, lb0);
            GLL(pb1 + kk, lb1);
            __syncthreads();
            bf16x8 af[4], bf[4];
            #pragma unroll
            for (int mi = 0; mi < 4; mi++)
                af[mi] = *(const bf16x8*)&sA[(mbase + mi * 16) * 32 + koff];
            #pragma unroll
            for (int ni = 0; ni < 4; ni++)
                bf[ni] = *(const bf16x8*)&sB[(nbase + ni * 16) * 32 + koff];
            #pragma unroll
            for (int mi = 0; mi < 4; mi++)
                #pragma unroll
                for (int ni = 0; ni < 4; ni++)
                    acc[mi][ni] = __builtin_amdgcn_mfma_f32_16x16x32_bf16(
                        af[mi], bf[ni], acc[mi][ni], 0, 0, 0);
            __syncthreads();
        }
        if (pass == 0) {
            #pragma unroll
            for (int mi = 0; mi < 4; mi++)
                #pragma unroll
                for (int ni = 0; ni < 4; ni++)
                    #pragma unroll
                    for (int r = 0; r < 4; r++)
                        res[mi][ni][r] = fmaxf(acc[mi][ni][r], 0.0f);
        }
    }

    const int crow = bm + (wave & 1) * 64 + (lane >> 4) * 4;
    const int ccol = bn + (wave >> 1) * 64 + (lane & 15);
    #pragma unroll
    for (int mi = 0; mi < 4; mi++)
        #pragma unroll
        for (int ni = 0; ni < 4; ni++)
            #pragma unroll
            for (int r = 0; r < 4; r++) {
                int row = crow + mi * 16 + r;
                if (row >= M) continue;
                int col = ccol + ni * 16;
                float v = alpha * (res[mi][ni][r] + fmaxf(acc[mi][ni][r], 0.0f));
                size_t idx = (size_t)row * Nc + col;
                if (outF) outF[idx] = v;
                else      outH[idx] = f2b(v);
            }
}

// ---------------- host orchestration ----------------

extern "C" void kernel_launch(void* const* d_in, const int* in_sizes, int n_in,
                              void* d_out, int out_size, void* d_ws, size_t ws_size,
                              hipStream_t stream) {
    const int F = 256;
    const int N = in_sizes[0] / F;
    const int PEd = in_sizes[1] / N;          // 98
    const int E = in_sizes[2] / 2;            // 800000
    const int KC = F + PEd;                   // 354
    const int KP = (KC + 31) & ~31;           // 384

    const float* x   = (const float*)d_in[0];
    const float* pe  = (const float*)d_in[1];
    const int*   ei0 = (const int*)d_in[2];
    const float* ea0 = (const float*)d_in[3];
    const int*   ei1 = (const int*)d_in[4];
    const float* ea1 = (const float*)d_in[5];
    const float* Wn1 = (const float*)d_in[6];
    const float* Wn2 = (const float*)d_in[7];
    const float* W11 = (const float*)d_in[8];
    const float* W12 = (const float*)d_in[9];
    const float* W21 = (const float*)d_in[10];
    const float* W22 = (const float*)d_in[11];
    const float* W31 = (const float*)d_in[12];
    const float* W32 = (const float*)d_in[13];
    const float* W41 = (const float*)d_in[14];
    const float* W42 = (const float*)d_in[15];
    float* out = (float*)d_out;

    char* p = (char*)d_ws;
    auto alloc = [&](size_t b) -> char* {
        char* r = p;
        p += (b + 255) & ~(size_t)255;
        return r;
    };
    int*   cnt0  = (int*)alloc((size_t)N * 4);
    int*   cnt1  = (int*)alloc((size_t)N * 4);
    int*   off0  = (int*)alloc((size_t)(N + 1) * 4);
    int*   off1  = (int*)alloc((size_t)(N + 1) * 4);
    int*   cur0  = (int*)alloc((size_t)N * 4);
    int*   cur1  = (int*)alloc((size_t)N * 4);
    float* dinv0 = (float*)alloc((size_t)N * 4);
    float* dinv1 = (float*)alloc((size_t)N * 4);
    int*   bs0   = (int*)alloc(64 * 4);
    int*   bs1   = (int*)alloc(64 * 4);
    uint2* rec0  = (uint2*)alloc(((size_t)E + 8ull * N) * 8);   // padded CSR
    uint2* rec1  = (uint2*)alloc(((size_t)E + 8ull * N) * 8);
    unsigned short* wn0c = (unsigned short*)alloc((size_t)F * KP * 2);
    unsigned short* wn1c = (unsigned short*)alloc((size_t)F * KP * 2);
    unsigned short* wc0  = (unsigned short*)alloc((size_t)F * 512 * 2);
    unsigned short* wc1  = (unsigned short*)alloc((size_t)F * 512 * 2);
    unsigned short* wc2  = (unsigned short*)alloc((size_t)F * 512 * 2);
    unsigned short* wc3  = (unsigned short*)alloc((size_t)F * 512 * 2);
    unsigned short* xa   = (unsigned short*)alloc((size_t)N * 512 * 2);  // xa|xb
    unsigned short* xb   = xa + (size_t)N * 256;
    unsigned short* h    = (unsigned short*)alloc((size_t)N * F * 2);
    unsigned short* a12  = (unsigned short*)alloc((size_t)N * 512 * 2);
    unsigned short* xc   = a12;                  // dead after node transforms
    unsigned short* a12bL1 = (unsigned short*)d_out;  // N*512 bf16 == out_size f32
    unsigned short* a12bL2 = xa;                 // xa|xb dead after layer-1 agg

    const int B = 256;
    const int gE = (E + B - 1) / B;
    const int gN = (N + B - 1) / B;
    const int gW = (N + 3) / 4;                  // 4 waves (nodes) per block
    const int nb = (N + 1023) / 1024;            // scan blocks
    dim3 gemm_grid((N + 127) / 128, 2);
    dim3 gemm_grid2((N + 127) / 128, 2, 2);

    // 1. degree / dinv / padded CSR (self-loop record included)
    hipMemsetAsync(cnt0, 0, (size_t)N * 4, stream);
    hipMemsetAsync(cnt1, 0, (size_t)N * 4, stream);
    k_cnt2<<<dim3(gE, 2), B, 0, stream>>>(ei0 + E, ei1 + E, E, cnt0, cnt1);
    k_scanA<<<dim3(nb, 2), 1024, 0, stream>>>(cnt0, cnt1, off0, off1, bs0, bs1, N);
    k_scanB<<<dim3(1, 2), 64, 0, stream>>>(bs0, bs1, nb);
    k_scanC<<<dim3(nb, 2), 1024, 0, stream>>>(bs0, bs1, off0, off1, N);
    k_prep<<<dim3(gN, 2), B, 0, stream>>>(cnt0, cnt1, off0, off1, dinv0, dinv1, cur0, cur1, N);
    k_fill2<<<dim3(gE, 2), B, 0, stream>>>(ei0, ea0, ei1, ea1, E, dinv0, dinv1,
                                           cur0, cur1, rec0, rec1);
    k_pad<<<dim3(gN, 2), B, 0, stream>>>(cnt0, cnt1, off0, off1, dinv0, dinv1,
                                         rec0, rec1, N);

    // 2. bf16 conversions
    k_xc<<<((size_t)N * KP + B - 1) / B, B, 0, stream>>>(x, pe, xc, N, F, PEd, KC, KP);
    {
        int tot = 2 * F * KP + 4 * F * 512;
        k_wall<<<(tot + B - 1) / B, B, 0, stream>>>(Wn1, Wn2, W11, W12, W21, W22,
                                                    W31, W32, W41, W42,
                                                    wn0c, wn1c, wc0, wc1, wc2, wc3,
                                                    F, KC, KP);
    }

    // 3. node transforms (both via blockIdx.z) -> xa, xb  [row-major N x 256]
    gemm_bt<<<gemm_grid2, B, 0, stream>>>(xc, wn0c, wn1c, N, KP, F, xa, xb);

    // 4. layer 1: both aggs in one dispatch; then dual GEMM -> h (bf16)
    k_agg<<<dim3(gW, 2), B, 0, stream>>>(xa, xb, off0, off1, rec0, rec1,
                                         a12, a12bL1, N);
    gemm_dual<<<gemm_grid, B, 0, stream>>>(a12, wc0, a12bL1, wc1, N, 512, F,
                                           nullptr, h, 0.5f);

    // 5. layer 2: both aggs in one dispatch; then dual GEMM -> out (f32)
    k_agg<<<dim3(gW, 2), B, 0, stream>>>(h, h, off0, off1, rec0, rec1,
                                         a12, a12bL2, N);
    gemm_dual<<<gemm_grid, B, 0, stream>>>(a12, wc2, a12bL2, wc3, N, 512, F,
                                           out, nullptr, 0.5f);
}

// Round 2
// 756.383 us; speedup vs baseline: 1.2218x; 1.2218x over previous
//
#include <hip/hip_runtime.h>

// ---------------------------------------------------------------------------
// GraphTrajSimEncoder on MI355X — round 8.
// R7 post-mortem: k_agg v3 regressed 117->218us. Culprit: `&g[k]` address-take
// blocked SROA -> AMDGPUPromoteAlloca moved uint4 g[4] into LDS (LDS_Block_Size
// 16384 = 256thr x 64B, SQ_LDS_BANK_CONFLICT 8.6e7 ~= 140us/CU). Scan fix was
// real (-60us on non-agg time). R8: same v3 dataflow, zero local arrays in the
// hot loop — all named scalars, component access only, macro-expanded FMA.
// ---------------------------------------------------------------------------

using bf16x8  = __attribute__((ext_vector_type(8))) __bf16;
using floatx4 = __attribute__((ext_vector_type(4))) float;
using f32x2   = __attribute__((ext_vector_type(2))) float;

__device__ __forceinline__ float b2f(unsigned short b) {
    return __uint_as_float(((unsigned)b) << 16);
}
__device__ __forceinline__ unsigned short f2b(float f) {
    unsigned u = __float_as_uint(f);
    return (unsigned short)((u + 0x7FFFu + ((u >> 16) & 1u)) >> 16);
}
__device__ __forceinline__ unsigned short f2h(float f) {
    _Float16 h = (_Float16)f;
    return __builtin_bit_cast(unsigned short, h);
}
__device__ __forceinline__ float h2f(unsigned short u) {
    return (float)__builtin_bit_cast(_Float16, u);
}

// ---------------- graph preprocessing ----------------

__global__ void k_cnt2(const int* __restrict__ col0, const int* __restrict__ col1,
                       int E, int* __restrict__ cnt0, int* __restrict__ cnt1) {
    int e = blockIdx.x * 256 + threadIdx.x;
    const int* col = blockIdx.y ? col1 : col0;
    int* cnt = blockIdx.y ? cnt1 : cnt0;
    if (e < E) atomicAdd(&cnt[col[e]], 1);
}

// 3-phase scan of padded counts. Pad = cnt + 1 (self record) rounded up to 8.
// Phase A: per-block (1024 elems) inclusive scan -> off[i+1] (local), block sum.
__global__ __launch_bounds__(1024) void k_scanA(
    const int* __restrict__ cnt0, const int* __restrict__ cnt1,
    int* __restrict__ off0, int* __restrict__ off1,
    int* __restrict__ bs0, int* __restrict__ bs1, int n) {
    const int* cnt = blockIdx.y ? cnt1 : cnt0;
    int* off = blockIdx.y ? off1 : off0;
    int* bs  = blockIdx.y ? bs1 : bs0;
    __shared__ int wsum[16];
    __shared__ int wpre[16];
    const int t = threadIdx.x;
    const int lane = t & 63;
    const int w = t >> 6;
    const int i = blockIdx.x * 1024 + t;
    int v = (i < n) ? ((cnt[i] + 8) & ~7) : 0;   // cnt + self, padded to x8
    #pragma unroll
    for (int d = 1; d < 64; d <<= 1) {
        int u = __shfl_up(v, d, 64);
        if (lane >= d) v += u;
    }
    if (lane == 63) wsum[w] = v;
    __syncthreads();
    if (t < 16) {
        int s2 = wsum[t];
        #pragma unroll
        for (int d = 1; d < 16; d <<= 1) {
            int u = __shfl_up(s2, d, 16);
            if (t >= d) s2 += u;
        }
        wpre[t] = s2;
    }
    __syncthreads();
    int incl = v + (w > 0 ? wpre[w - 1] : 0);
    if (i < n) off[i + 1] = incl;
    if (t == 1023) bs[blockIdx.x] = incl;
}

// Phase B: one wave scans the (<=64) block sums -> exclusive prefixes in place.
__global__ void k_scanB(int* __restrict__ bs0, int* __restrict__ bs1, int nb) {
    int* bs = blockIdx.y ? bs1 : bs0;
    const int t = threadIdx.x;       // 64 threads
    int v = (t < nb) ? bs[t] : 0;
    int orig = v;
    #pragma unroll
    for (int d = 1; d < 64; d <<= 1) {
        int u = __shfl_up(v, d, 64);
        if (t >= d) v += u;
    }
    if (t < nb) bs[t] = v - orig;    // exclusive
}

// Phase C: add block prefix; set off[0]=0.
__global__ __launch_bounds__(1024) void k_scanC(
    const int* __restrict__ bs0, const int* __restrict__ bs1,
    int* __restrict__ off0, int* __restrict__ off1, int n) {
    int* off = blockIdx.y ? off1 : off0;
    const int* bs = blockIdx.y ? bs1 : bs0;
    const int i = blockIdx.x * 1024 + threadIdx.x;
    if (i == 0) off[0] = 0;
    if (i < n && blockIdx.x > 0) off[i + 1] += bs[blockIdx.x];
}

// dinv = rsqrt(REAL deg + 1), cur = off  — grid (gN,2)
__global__ void k_prep(const int* __restrict__ cnt0, const int* __restrict__ cnt1,
                       const int* __restrict__ off0, const int* __restrict__ off1,
                       float* __restrict__ dinv0, float* __restrict__ dinv1,
                       int* __restrict__ cur0, int* __restrict__ cur1, int n) {
    int i = blockIdx.x * 256 + threadIdx.x;
    if (i >= n) return;
    const int* cnt = blockIdx.y ? cnt1 : cnt0;
    const int* off = blockIdx.y ? off1 : off0;
    float* dinv = blockIdx.y ? dinv1 : dinv0;
    int* cur = blockIdx.y ? cur1 : cur0;
    dinv[i] = rsqrtf((float)(cnt[i] + 1));
    cur[i] = off[i];
}

// CSR fill: 8B record per edge = (src:u32, (fp16 w1)<<16 | fp16 w2).
__global__ void k_fill2(const int* __restrict__ ei0, const float* __restrict__ ea0,
                        const int* __restrict__ ei1, const float* __restrict__ ea1,
                        int E, const float* __restrict__ dinv0,
                        const float* __restrict__ dinv1,
                        int* __restrict__ cur0, int* __restrict__ cur1,
                        uint2* __restrict__ rec0, uint2* __restrict__ rec1) {
    int e = blockIdx.x * 256 + threadIdx.x;
    if (e >= E) return;
    const int* ei = blockIdx.y ? ei1 : ei0;
    const float* ea = blockIdx.y ? ea1 : ea0;
    const float* dinv = blockIdx.y ? dinv1 : dinv0;
    int* cur = blockIdx.y ? cur1 : cur0;
    uint2* rec = blockIdx.y ? rec1 : rec0;
    int r = ei[e];          // source
    int c = ei[E + e];      // target
    float a = ea[e];
    float w2 = (a > 0.0f) ? fminf(rsqrtf(a), 1.0f) : 0.0f;
    float w1 = dinv[r] * dinv[c];
    int p = atomicAdd(&cur[c], 1);
    rec[p] = make_uint2((unsigned)r,
                        ((unsigned)f2h(w1) << 16) | (unsigned)f2h(w2));
}

// self-loop record (w1 = dinv^2, w2 = 1.0) + zero-pad tail — grid (gN,2)
__global__ void k_pad(const int* __restrict__ cnt0, const int* __restrict__ cnt1,
                      const int* __restrict__ off0, const int* __restrict__ off1,
                      const float* __restrict__ dinv0, const float* __restrict__ dinv1,
                      uint2* __restrict__ rec0, uint2* __restrict__ rec1, int n) {
    int i = blockIdx.x * 256 + threadIdx.x;
    if (i >= n) return;
    const int* cnt = blockIdx.y ? cnt1 : cnt0;
    const int* off = blockIdx.y ? off1 : off0;
    const float* dinv = blockIdx.y ? dinv1 : dinv0;
    uint2* rec = blockIdx.y ? rec1 : rec0;
    int p = off[i] + cnt[i], pe = off[i + 1];
    float di = dinv[i];
    rec[p++] = make_uint2((unsigned)i,
                          ((unsigned)f2h(di * di) << 16) | 0x3C00u);  // w2 = 1.0
    for (; p < pe; ++p) rec[p] = make_uint2(0u, 0u);
}

// ---------------- dtype conversions ----------------

// xc[i][k] (bf16, K padded to KP): k<F -> x, k<KC -> d2an, else 0  (row-major)
__global__ void k_xc(const float* __restrict__ x, const float* __restrict__ pe,
                     unsigned short* __restrict__ xc, int n, int F, int PEd,
                     int KC, int KP) {
    int idx = blockIdx.x * 256 + threadIdx.x;
    if (idx >= n * KP) return;
    int i = idx / KP, k = idx - i * KP;
    float v = 0.0f;
    if (k < F)        v = x[(size_t)i * F + k];
    else if (k < KC)  v = pe[(size_t)i * PEd + (k - F)];
    xc[idx] = f2b(v);
}

// weight conversions (row-major K):
//   seg 0/1: Wn [F][KC] f32 -> [F][KP] bf16 zero-padded
//   seg 2..5: [Wa|Wb] pairs -> [F][512] bf16 plain concat
__global__ void k_wall(const float* __restrict__ Wn1, const float* __restrict__ Wn2,
                       const float* __restrict__ W11, const float* __restrict__ W12,
                       const float* __restrict__ W21, const float* __restrict__ W22,
                       const float* __restrict__ W31, const float* __restrict__ W32,
                       const float* __restrict__ W41, const float* __restrict__ W42,
                       unsigned short* __restrict__ wn0c, unsigned short* __restrict__ wn1c,
                       unsigned short* __restrict__ wc0, unsigned short* __restrict__ wc1,
                       unsigned short* __restrict__ wc2, unsigned short* __restrict__ wc3,
                       int F, int KC, int KP) {
    int idx = blockIdx.x * 256 + threadIdx.x;
    int npad = F * KP;
    if (idx < 2 * npad) {
        const float* W = (idx < npad) ? Wn1 : Wn2;
        unsigned short* Wc = (idx < npad) ? wn0c : wn1c;
        int t = (idx < npad) ? idx : idx - npad;
        int o = t / KP, k = t - o * KP;
        Wc[t] = f2b(k < KC ? W[(size_t)o * KC + k] : 0.0f);
        return;
    }
    int t = idx - 2 * npad;
    int seg = F * 512;
    if (t >= 4 * seg) return;
    int which = t / seg;
    int r = t - which * seg;
    const float* Wa = (which == 0) ? W11 : (which == 1) ? W21 : (which == 2) ? W31 : W41;
    const float* Wb = (which == 0) ? W12 : (which == 1) ? W22 : (which == 2) ? W32 : W42;
    unsigned short* Wc = (which == 0) ? wc0 : (which == 1) ? wc1 : (which == 2) ? wc2 : wc3;
    int o = r >> 9, k = r & 511;
    float v = (k < 256) ? Wa[(size_t)o * 256 + k] : Wb[(size_t)o * 256 + (k - 256)];
    Wc[r] = f2b(v);
}

// ---------------- CSR gather-aggregation v4 ----------------
// One wave per node. Lanes 0-31 process even-indexed records, 32-63 odd ones:
// each gather is a dwordx4 (16B/lane, 8 feats) covering 2 edges per instr.
// Self loop is an ordinary CSR record; zero-pad records are (row0, w=0).
// NO local arrays / address-takes in the hot loop (R7 lesson: &g[k] ->
// PromoteAlloca -> LDS spill + 8.6e7 bank-conflict cycles). All named scalars.
// Epilogue: cross-half shfl_xor(32) combine; lanes<32 write a1, lanes>=32 a2.
// Output A[i] = [a1(256) | a2(256)] bf16.

#define AGG_SLOT(g, wsel)                                                     \
    do {                                                                      \
        float w1 = h2f((unsigned short)((wsel) >> 16));                       \
        float w2 = h2f((unsigned short)((wsel) & 0xFFFFu));                   \
        f32x2 w1v = {w1, w1};                                                 \
        f32x2 w2v = {w2, w2};                                                 \
        f32x2 v;                                                              \
        v.x = __uint_as_float((g).x << 16);                                   \
        v.y = __uint_as_float((g).x & 0xFFFF0000u);                           \
        c1a = __builtin_elementwise_fma(w1v, v, c1a);                         \
        c2a = __builtin_elementwise_fma(w2v, v, c2a);                         \
        v.x = __uint_as_float((g).y << 16);                                   \
        v.y = __uint_as_float((g).y & 0xFFFF0000u);                           \
        c1b = __builtin_elementwise_fma(w1v, v, c1b);                         \
        c2b = __builtin_elementwise_fma(w2v, v, c2b);                         \
        v.x = __uint_as_float((g).z << 16);                                   \
        v.y = __uint_as_float((g).z & 0xFFFF0000u);                           \
        c1c = __builtin_elementwise_fma(w1v, v, c1c);                         \
        c2c = __builtin_elementwise_fma(w2v, v, c2c);                         \
        v.x = __uint_as_float((g).w << 16);                                   \
        v.y = __uint_as_float((g).w & 0xFFFF0000u);                           \
        c1d = __builtin_elementwise_fma(w1v, v, c1d);                         \
        c2d = __builtin_elementwise_fma(w2v, v, c2d);                         \
    } while (0)

__global__ __launch_bounds__(256) void k_agg(
    const unsigned short* __restrict__ X0, const unsigned short* __restrict__ X1,
    const int* __restrict__ off0, const int* __restrict__ off1,
    const uint2* __restrict__ rec0, const uint2* __restrict__ rec1,
    unsigned short* __restrict__ A0, unsigned short* __restrict__ A1, int n) {
    const int s = blockIdx.y;
    const char* Xb = (const char*)(s ? X1 : X0);
    const int* off = s ? off1 : off0;
    const uint2* rec = s ? rec1 : rec0;
    unsigned short* A = s ? A1 : A0;

    const int gw = (blockIdx.x * 256 + threadIdx.x) >> 6;
    const int lane = threadIdx.x & 63;
    if (gw >= n) return;

    const int e0 = __builtin_amdgcn_readfirstlane(off[gw]);
    const int e1 = __builtin_amdgcn_readfirstlane(off[gw + 1]);
    const bool hi = lane >= 32;
    const unsigned loff = (unsigned)(lane & 31) << 4;   // 16B chunk within row

    f32x2 c1a = {0.f, 0.f}, c1b = {0.f, 0.f}, c1c = {0.f, 0.f}, c1d = {0.f, 0.f};
    f32x2 c2a = {0.f, 0.f}, c2b = {0.f, 0.f}, c2c = {0.f, 0.f}, c2d = {0.f, 0.f};

    const uint4* recq = (const uint4*)(rec + e0);   // 1 uint4 = 2 records
    const int nit = (e1 - e0) >> 3;                 // 8 records / iter
    for (int it = 0; it < nit; ++it) {
        uint4 qa = recq[it * 4 + 0];                // broadcast loads
        uint4 qb = recq[it * 4 + 1];
        uint4 qc = recq[it * 4 + 2];
        uint4 qd = recq[it * 4 + 3];
        unsigned sa = hi ? qa.z : qa.x, wa = hi ? qa.w : qa.y;
        unsigned sb = hi ? qb.z : qb.x, wb = hi ? qb.w : qb.y;
        unsigned sc = hi ? qc.z : qc.x, wcs = hi ? qc.w : qc.y;
        unsigned sd = hi ? qd.z : qd.x, wd = hi ? qd.w : qd.y;
        uint4 ga = *(const uint4*)(Xb + ((sa << 9) | loff));
        uint4 gb = *(const uint4*)(Xb + ((sb << 9) | loff));
        uint4 gc = *(const uint4*)(Xb + ((sc << 9) | loff));
        uint4 gd = *(const uint4*)(Xb + ((sd << 9) | loff));
        AGG_SLOT(ga, wa);
        AGG_SLOT(gb, wb);
        AGG_SLOT(gc, wcs);
        AGG_SLOT(gd, wd);
    }

    // combine halves (lane L and L^32 hold the same 8 feats over disjoint edges)
    float u0 = c1a.x + __shfl_xor(c1a.x, 32);
    float u1 = c1a.y + __shfl_xor(c1a.y, 32);
    float u2 = c1b.x + __shfl_xor(c1b.x, 32);
    float u3 = c1b.y + __shfl_xor(c1b.y, 32);
    float u4 = c1c.x + __shfl_xor(c1c.x, 32);
    float u5 = c1c.y + __shfl_xor(c1c.y, 32);
    float u6 = c1d.x + __shfl_xor(c1d.x, 32);
    float u7 = c1d.y + __shfl_xor(c1d.y, 32);
    float t0 = c2a.x + __shfl_xor(c2a.x, 32);
    float t1 = c2a.y + __shfl_xor(c2a.y, 32);
    float t2 = c2b.x + __shfl_xor(c2b.x, 32);
    float t3 = c2b.y + __shfl_xor(c2b.y, 32);
    float t4 = c2c.x + __shfl_xor(c2c.x, 32);
    float t5 = c2c.y + __shfl_xor(c2c.y, 32);
    float t6 = c2d.x + __shfl_xor(c2d.x, 32);
    float t7 = c2d.y + __shfl_xor(c2d.y, 32);

    float s0 = hi ? t0 : u0;
    float s1 = hi ? t1 : u1;
    float s2 = hi ? t2 : u2;
    float s3 = hi ? t3 : u3;
    float s4 = hi ? t4 : u4;
    float s5 = hi ? t5 : u5;
    float s6 = hi ? t6 : u6;
    float s7 = hi ? t7 : u7;
    uint4 o;
    o.x = (unsigned)f2b(s0) | ((unsigned)f2b(s1) << 16);
    o.y = (unsigned)f2b(s2) | ((unsigned)f2b(s3) << 16);
    o.z = (unsigned)f2b(s4) | ((unsigned)f2b(s5) << 16);
    o.w = (unsigned)f2b(s6) | ((unsigned)f2b(s7) << 16);
    *(uint4*)(A + (size_t)gw * 512 + (hi ? 256 : 0) + ((lane & 31) << 3)) = o;
}

// ---------------- bf16 MFMA GEMM kernels ----------------
#define GLL(g, l) \
    __builtin_amdgcn_global_load_lds((__attribute__((address_space(1))) void*)(g), \
                                     (__attribute__((address_space(3))) void*)(l), 16, 0, 0)

// node-transform GEMM: C[M][Nc] = A[M][K] @ B[Nc][K]^T, bf16 out, z selects B/out.
__global__ __launch_bounds__(256) void gemm_bt(
    const unsigned short* __restrict__ A,
    const unsigned short* __restrict__ B0, const unsigned short* __restrict__ B1,
    int M, int K, int Nc,
    unsigned short* __restrict__ outH0, unsigned short* __restrict__ outH1) {
    const unsigned short* B = blockIdx.z ? B1 : B0;
    unsigned short* outH = blockIdx.z ? outH1 : outH0;

    __shared__ __align__(16) unsigned short sA[128 * 32];
    __shared__ __align__(16) unsigned short sB[128 * 32];
    const int tid = threadIdx.x;
    const int lane = tid & 63;
    const int wave = tid >> 6;
    const int bm = blockIdx.x * 128;
    const int bn = blockIdx.y * 128;

    const int r0 = wave * 32 + (lane >> 2);
    const int kcol = (lane & 3) * 8;
    const int ga0 = min(bm + r0, M - 1);
    const int ga1 = min(bm + r0 + 16, M - 1);
    const int gb0 = min(bn + r0, Nc - 1);
    const int gb1 = min(bn + r0 + 16, Nc - 1);
    const unsigned short* pa0 = A + (size_t)ga0 * K + kcol;
    const unsigned short* pa1 = A + (size_t)ga1 * K + kcol;
    const unsigned short* pb0 = B + (size_t)gb0 * K + kcol;
    const unsigned short* pb1 = B + (size_t)gb1 * K + kcol;
    unsigned short* la0 = &sA[wave * 1024];
    unsigned short* la1 = &sA[wave * 1024 + 512];
    unsigned short* lb0 = &sB[wave * 1024];
    unsigned short* lb1 = &sB[wave * 1024 + 512];

    floatx4 acc[4][4];
    #pragma unroll
    for (int i = 0; i < 4; i++)
        #pragma unroll
        for (int j = 0; j < 4; j++) acc[i][j] = (floatx4){0.f, 0.f, 0.f, 0.f};

    const int mbase = (wave & 1) * 64 + (lane & 15);
    const int nbase = (wave >> 1) * 64 + (lane & 15);
    const int koff = (lane >> 4) * 8;

    for (int kk = 0; kk < K; kk += 32) {
        GLL(pa0 + kk, la0);
        GLL(pa1 + kk, la1);
        GLL(pb0 + kk, lb0);
        GLL(pb1 + kk, lb1);
        __syncthreads();
        bf16x8 af[4], bf[4];
        #pragma unroll
        for (int mi = 0; mi < 4; mi++)
            af[mi] = *(const bf16x8*)&sA[(mbase + mi * 16) * 32 + koff];
        #pragma unroll
        for (int ni = 0; ni < 4; ni++)
            bf[ni] = *(const bf16x8*)&sB[(nbase + ni * 16) * 32 + koff];
        #pragma unroll
        for (int mi = 0; mi < 4; mi++)
            #pragma unroll
            for (int ni = 0; ni < 4; ni++)
                acc[mi][ni] = __builtin_amdgcn_mfma_f32_16x16x32_bf16(
                    af[mi], bf[ni], acc[mi][ni], 0, 0, 0);
        __syncthreads();
    }

    const int crow = bm + (wave & 1) * 64 + (lane >> 4) * 4;
    const int ccol = bn + (wave >> 1) * 64 + (lane & 15);
    #pragma unroll
    for (int mi = 0; mi < 4; mi++)
        #pragma unroll
        for (int ni = 0; ni < 4; ni++)
            #pragma unroll
            for (int r = 0; r < 4; r++) {
                int row = crow + mi * 16 + r;
                if (row >= M) continue;
                int col = ccol + ni * 16;
                outH[(size_t)row * Nc + col] = f2b(acc[mi][ni][r]);
            }
}

// dual GEMM: C = 0.5*relu(A0@B0^T) + 0.5*relu(A1@B1^T); out f32 or bf16.
__global__ __launch_bounds__(256) void gemm_dual(
    const unsigned short* __restrict__ A0, const unsigned short* __restrict__ B0,
    const unsigned short* __restrict__ A1, const unsigned short* __restrict__ B1,
    int M, int K, int Nc,
    float* __restrict__ outF, unsigned short* __restrict__ outH, float alpha) {
    __shared__ __align__(16) unsigned short sA[128 * 32];
    __shared__ __align__(16) unsigned short sB[128 * 32];
    const int tid = threadIdx.x;
    const int lane = tid & 63;
    const int wave = tid >> 6;
    const int bm = blockIdx.x * 128;
    const int bn = blockIdx.y * 128;

    const int r0 = wave * 32 + (lane >> 2);
    const int kcol = (lane & 3) * 8;
    const int ga0 = min(bm + r0, M - 1);
    const int ga1 = min(bm + r0 + 16, M - 1);
    const int gb0 = min(bn + r0, Nc - 1);
    const int gb1 = min(bn + r0 + 16, Nc - 1);
    unsigned short* la0 = &sA[wave * 1024];
    unsigned short* la1 = &sA[wave * 1024 + 512];
    unsigned short* lb0 = &sB[wave * 1024];
    unsigned short* lb1 = &sB[wave * 1024 + 512];

    const int mbase = (wave & 1) * 64 + (lane & 15);
    const int nbase = (wave >> 1) * 64 + (lane & 15);
    const int koff = (lane >> 4) * 8;

    floatx4 acc[4][4], res[4][4];

    #pragma unroll
    for (int pass = 0; pass < 2; pass++) {
        const unsigned short* A = pass ? A1 : A0;
        const unsigned short* B = pass ? B1 : B0;
        const unsigned short* pa0 = A + (size_t)ga0 * K + kcol;
        const unsigned short* pa1 = A + (size_t)ga1 * K + kcol;
        const unsigned short* pb0 = B + (size_t)gb0 * K + kcol;
        const unsigned short* pb1 = B + (size_t)gb1 * K + kcol;
        #pragma unroll
        for (int i = 0; i < 4; i++)
            #pragma unroll
            for (int j = 0; j < 4; j++) acc[i][j] = (floatx4){0.f, 0.f, 0.f, 0.f};

        for (int kk = 0; kk < K; kk += 32) {
            GLL(pa0 + kk, la0);
            GLL(pa1 + kk, la1);
            GLL(pb0 + kk, lb0);
            GLL(pb1 + kk, lb1);
            __syncthreads();
            bf16x8 af[4], bf[4];
            #pragma unroll
            for (int mi = 0; mi < 4; mi++)
                af[mi] = *(const bf16x8*)&sA[(mbase + mi * 16) * 32 + koff];
            #pragma unroll
            for (int ni = 0; ni < 4; ni++)
                bf[ni] = *(const bf16x8*)&sB[(nbase + ni * 16) * 32 + koff];
            #pragma unroll
            for (int mi = 0; mi < 4; mi++)
                #pragma unroll
                for (int ni = 0; ni < 4; ni++)
                    acc[mi][ni] = __builtin_amdgcn_mfma_f32_16x16x32_bf16(
                        af[mi], bf[ni], acc[mi][ni], 0, 0, 0);
            __syncthreads();
        }
        if (pass == 0) {
            #pragma unroll
            for (int mi = 0; mi < 4; mi++)
                #pragma unroll
                for (int ni = 0; ni < 4; ni++)
                    #pragma unroll
                    for (int r = 0; r < 4; r++)
                        res[mi][ni][r] = fmaxf(acc[mi][ni][r], 0.0f);
        }
    }

    const int crow = bm + (wave & 1) * 64 + (lane >> 4) * 4;
    const int ccol = bn + (wave >> 1) * 64 + (lane & 15);
    #pragma unroll
    for (int mi = 0; mi < 4; mi++)
        #pragma unroll
        for (int ni = 0; ni < 4; ni++)
            #pragma unroll
            for (int r = 0; r < 4; r++) {
                int row = crow + mi * 16 + r;
                if (row >= M) continue;
                int col = ccol + ni * 16;
                float v = alpha * (res[mi][ni][r] + fmaxf(acc[mi][ni][r], 0.0f));
                size_t idx = (size_t)row * Nc + col;
                if (outF) outF[idx] = v;
                else      outH[idx] = f2b(v);
            }
}

// ---------------- host orchestration ----------------

extern "C" void kernel_launch(void* const* d_in, const int* in_sizes, int n_in,
                              void* d_out, int out_size, void* d_ws, size_t ws_size,
                              hipStream_t stream) {
    const int F = 256;
    const int N = in_sizes[0] / F;
    const int PEd = in_sizes[1] / N;          // 98
    const int E = in_sizes[2] / 2;            // 800000
    const int KC = F + PEd;                   // 354
    const int KP = (KC + 31) & ~31;           // 384

    const float* x   = (const float*)d_in[0];
    const float* pe  = (const float*)d_in[1];
    const int*   ei0 = (const int*)d_in[2];
    const float* ea0 = (const float*)d_in[3];
    const int*   ei1 = (const int*)d_in[4];
    const float* ea1 = (const float*)d_in[5];
    const float* Wn1 = (const float*)d_in[6];
    const float* Wn2 = (const float*)d_in[7];
    const float* W11 = (const float*)d_in[8];
    const float* W12 = (const float*)d_in[9];
    const float* W21 = (const float*)d_in[10];
    const float* W22 = (const float*)d_in[11];
    const float* W31 = (const float*)d_in[12];
    const float* W32 = (const float*)d_in[13];
    const float* W41 = (const float*)d_in[14];
    const float* W42 = (const float*)d_in[15];
    float* out = (float*)d_out;

    char* p = (char*)d_ws;
    auto alloc = [&](size_t b) -> char* {
        char* r = p;
        p += (b + 255) & ~(size_t)255;
        return r;
    };
    int*   cnt0  = (int*)alloc((size_t)N * 4);
    int*   cnt1  = (int*)alloc((size_t)N * 4);
    int*   off0  = (int*)alloc((size_t)(N + 1) * 4);
    int*   off1  = (int*)alloc((size_t)(N + 1) * 4);
    int*   cur0  = (int*)alloc((size_t)N * 4);
    int*   cur1  = (int*)alloc((size_t)N * 4);
    float* dinv0 = (float*)alloc((size_t)N * 4);
    float* dinv1 = (float*)alloc((size_t)N * 4);
    int*   bs0   = (int*)alloc(64 * 4);
    int*   bs1   = (int*)alloc(64 * 4);
    uint2* rec0  = (uint2*)alloc(((size_t)E + 8ull * N) * 8);   // padded CSR
    uint2* rec1  = (uint2*)alloc(((size_t)E + 8ull * N) * 8);
    unsigned short* wn0c = (unsigned short*)alloc((size_t)F * KP * 2);
    unsigned short* wn1c = (unsigned short*)alloc((size_t)F * KP * 2);
    unsigned short* wc0  = (unsigned short*)alloc((size_t)F * 512 * 2);
    unsigned short* wc1  = (unsigned short*)alloc((size_t)F * 512 * 2);
    unsigned short* wc2  = (unsigned short*)alloc((size_t)F * 512 * 2);
    unsigned short* wc3  = (unsigned short*)alloc((size_t)F * 512 * 2);
    unsigned short* xa   = (unsigned short*)alloc((size_t)N * 512 * 2);  // xa|xb
    unsigned short* xb   = xa + (size_t)N * 256;
    unsigned short* h    = (unsigned short*)alloc((size_t)N * F * 2);
    unsigned short* a12  = (unsigned short*)alloc((size_t)N * 512 * 2);
    unsigned short* xc   = a12;                  // dead after node transforms
    unsigned short* a12bL1 = (unsigned short*)d_out;  // N*512 bf16 == out_size f32
    unsigned short* a12bL2 = xa;                 // xa|xb dead after layer-1 agg

    const int B = 256;
    const int gE = (E + B - 1) / B;
    const int gN = (N + B - 1) / B;
    const int gW = (N + 3) / 4;                  // 4 waves (nodes) per block
    const int nb = (N + 1023) / 1024;            // scan blocks
    dim3 gemm_grid((N + 127) / 128, 2);
    dim3 gemm_grid2((N + 127) / 128, 2, 2);

    // 1. degree / dinv / padded CSR (self-loop record included)
    hipMemsetAsync(cnt0, 0, (size_t)N * 4, stream);
    hipMemsetAsync(cnt1, 0, (size_t)N * 4, stream);
    k_cnt2<<<dim3(gE, 2), B, 0, stream>>>(ei0 + E, ei1 + E, E, cnt0, cnt1);
    k_scanA<<<dim3(nb, 2), 1024, 0, stream>>>(cnt0, cnt1, off0, off1, bs0, bs1, N);
    k_scanB<<<dim3(1, 2), 64, 0, stream>>>(bs0, bs1, nb);
    k_scanC<<<dim3(nb, 2), 1024, 0, stream>>>(bs0, bs1, off0, off1, N);
    k_prep<<<dim3(gN, 2), B, 0, stream>>>(cnt0, cnt1, off0, off1, dinv0, dinv1, cur0, cur1, N);
    k_fill2<<<dim3(gE, 2), B, 0, stream>>>(ei0, ea0, ei1, ea1, E, dinv0, dinv1,
                                           cur0, cur1, rec0, rec1);
    k_pad<<<dim3(gN, 2), B, 0, stream>>>(cnt0, cnt1, off0, off1, dinv0, dinv1,
                                         rec0, rec1, N);

    // 2. bf16 conversions
    k_xc<<<((size_t)N * KP + B - 1) / B, B, 0, stream>>>(x, pe, xc, N, F, PEd, KC, KP);
    {
        int tot = 2 * F * KP + 4 * F * 512;
        k_wall<<<(tot + B - 1) / B, B, 0, stream>>>(Wn1, Wn2, W11, W12, W21, W22,
                                                    W31, W32, W41, W42,
                                                    wn0c, wn1c, wc0, wc1, wc2, wc3,
                                                    F, KC, KP);
    }

    // 3. node transforms (both via blockIdx.z) -> xa, xb  [row-major N x 256]
    gemm_bt<<<gemm_grid2, B, 0, stream>>>(xc, wn0c, wn1c, N, KP, F, xa, xb);

    // 4. layer 1: both aggs in one dispatch; then dual GEMM -> h (bf16)
    k_agg<<<dim3(gW, 2), B, 0, stream>>>(xa, xb, off0, off1, rec0, rec1,
                                         a12, a12bL1, N);
    gemm_dual<<<gemm_grid, B, 0, stream>>>(a12, wc0, a12bL1, wc1, N, 512, F,
                                           nullptr, h, 0.5f);

    // 5. layer 2: both aggs in one dispatch; then dual GEMM -> out (f32)
    k_agg<<<dim3(gW, 2), B, 0, stream>>>(h, h, off0, off1, rec0, rec1,
                                         a12, a12bL2, N);
    gemm_dual<<<gemm_grid, B, 0, stream>>>(a12, wc2, a12bL2, wc3, N, 512, F,
                                           out, nullptr, 0.5f);
}

// Round 3
// 725.463 us; speedup vs baseline: 1.2739x; 1.0426x over previous
//
#include <hip/hip_runtime.h>

// ---------------------------------------------------------------------------
// GraphTrajSimEncoder on MI355X — round 9.
// R8 post-mortem: k_agg v4 clean (no LDS spill) but latency-bound: VALU 48%,
// HBM 49%, serial chain s_load->addr->gather->FMA per iter. R9:
//  - k_agg v5: depth-1 software pipeline (prefetch next records+gathers while
//    consuming current), unroll 2 to kill rotation moves
//  - k_prep fused into k_scanC; k_pad fused into k_fill2 (one dispatch)
//  - k_xc vectorized: 8 bf16 per thread (float4 loads, uint4 stores)
// ---------------------------------------------------------------------------

using bf16x8  = __attribute__((ext_vector_type(8))) __bf16;
using floatx4 = __attribute__((ext_vector_type(4))) float;
using f32x2   = __attribute__((ext_vector_type(2))) float;

__device__ __forceinline__ unsigned short f2b(float f) {
    unsigned u = __float_as_uint(f);
    return (unsigned short)((u + 0x7FFFu + ((u >> 16) & 1u)) >> 16);
}
__device__ __forceinline__ unsigned short f2h(float f) {
    _Float16 h = (_Float16)f;
    return __builtin_bit_cast(unsigned short, h);
}
__device__ __forceinline__ float h2f(unsigned short u) {
    return (float)__builtin_bit_cast(_Float16, u);
}

// ---------------- graph preprocessing ----------------

__global__ void k_cnt2(const int* __restrict__ col0, const int* __restrict__ col1,
                       int E, int* __restrict__ cnt0, int* __restrict__ cnt1) {
    int e = blockIdx.x * 256 + threadIdx.x;
    const int* col = blockIdx.y ? col1 : col0;
    int* cnt = blockIdx.y ? cnt1 : cnt0;
    if (e < E) atomicAdd(&cnt[col[e]], 1);
}

// 3-phase scan of padded counts. Pad = cnt + 1 (self record) rounded up to 8.
// Phase A: per-block (1024 elems) inclusive scan -> off[i+1] (local), block sum.
__global__ __launch_bounds__(1024) void k_scanA(
    const int* __restrict__ cnt0, const int* __restrict__ cnt1,
    int* __restrict__ off0, int* __restrict__ off1,
    int* __restrict__ bs0, int* __restrict__ bs1, int n) {
    const int* cnt = blockIdx.y ? cnt1 : cnt0;
    int* off = blockIdx.y ? off1 : off0;
    int* bs  = blockIdx.y ? bs1 : bs0;
    __shared__ int wsum[16];
    __shared__ int wpre[16];
    const int t = threadIdx.x;
    const int lane = t & 63;
    const int w = t >> 6;
    const int i = blockIdx.x * 1024 + t;
    int v = (i < n) ? ((cnt[i] + 8) & ~7) : 0;   // cnt + self, padded to x8
    #pragma unroll
    for (int d = 1; d < 64; d <<= 1) {
        int u = __shfl_up(v, d, 64);
        if (lane >= d) v += u;
    }
    if (lane == 63) wsum[w] = v;
    __syncthreads();
    if (t < 16) {
        int s2 = wsum[t];
        #pragma unroll
        for (int d = 1; d < 16; d <<= 1) {
            int u = __shfl_up(s2, d, 16);
            if (t >= d) s2 += u;
        }
        wpre[t] = s2;
    }
    __syncthreads();
    int incl = v + (w > 0 ? wpre[w - 1] : 0);
    if (i < n) off[i + 1] = incl;
    if (t == 1023) bs[blockIdx.x] = incl;
}

// Phase B: one wave scans the (<=64) block sums -> exclusive prefixes in place.
__global__ void k_scanB(int* __restrict__ bs0, int* __restrict__ bs1, int nb) {
    int* bs = blockIdx.y ? bs1 : bs0;
    const int t = threadIdx.x;       // 64 threads
    int v = (t < nb) ? bs[t] : 0;
    int orig = v;
    #pragma unroll
    for (int d = 1; d < 64; d <<= 1) {
        int u = __shfl_up(v, d, 64);
        if (t >= d) v += u;
    }
    if (t < nb) bs[t] = v - orig;    // exclusive
}

// Phase C: add block prefix; set off[0]=0; fused k_prep:
//   cur[i] = final off[i] = off[i+1] - padded(cnt[i]); dinv[i] = rsqrt(cnt+1).
__global__ __launch_bounds__(1024) void k_scanC(
    const int* __restrict__ bs0, const int* __restrict__ bs1,
    const int* __restrict__ cnt0, const int* __restrict__ cnt1,
    int* __restrict__ off0, int* __restrict__ off1,
    float* __restrict__ dinv0, float* __restrict__ dinv1,
    int* __restrict__ cur0, int* __restrict__ cur1, int n) {
    int* off = blockIdx.y ? off1 : off0;
    const int* bs = blockIdx.y ? bs1 : bs0;
    const int* cnt = blockIdx.y ? cnt1 : cnt0;
    float* dinv = blockIdx.y ? dinv1 : dinv0;
    int* cur = blockIdx.y ? cur1 : cur0;
    const int i = blockIdx.x * 1024 + threadIdx.x;
    if (i == 0) off[0] = 0;
    if (i < n) {
        int ci = cnt[i];
        int o = off[i + 1] + (blockIdx.x > 0 ? bs[blockIdx.x] : 0);
        off[i + 1] = o;
        cur[i] = o - ((ci + 8) & ~7);
        dinv[i] = rsqrtf((float)(ci + 1));
    }
}

// Fused CSR fill + self-loop/pad. Threads [0, EB) fill edges; [EB, EB+n) pad.
// Edge record: (src:u32, (fp16 w1)<<16 | fp16 w2). Self: w1=dinv^2, w2=1.
__global__ void k_fillpad(
    const int* __restrict__ ei0, const float* __restrict__ ea0,
    const int* __restrict__ ei1, const float* __restrict__ ea1,
    int E, int EB,
    const int* __restrict__ cnt0, const int* __restrict__ cnt1,
    const int* __restrict__ off0, const int* __restrict__ off1,
    const float* __restrict__ dinv0, const float* __restrict__ dinv1,
    int* __restrict__ cur0, int* __restrict__ cur1,
    uint2* __restrict__ rec0, uint2* __restrict__ rec1, int n) {
    const int s = blockIdx.y;
    const float* dinv = s ? dinv1 : dinv0;
    uint2* rec = s ? rec1 : rec0;
    int t = blockIdx.x * 256 + threadIdx.x;
    if (t < EB) {
        int e = t;
        if (e >= E) return;
        const int* ei = s ? ei1 : ei0;
        const float* ea = s ? ea1 : ea0;
        int* cur = s ? cur1 : cur0;
        int r = ei[e];          // source
        int c = ei[E + e];      // target
        float a = ea[e];
        float w2 = (a > 0.0f) ? fminf(rsqrtf(a), 1.0f) : 0.0f;
        float w1 = dinv[r] * dinv[c];
        int p = atomicAdd(&cur[c], 1);
        rec[p] = make_uint2((unsigned)r,
                            ((unsigned)f2h(w1) << 16) | (unsigned)f2h(w2));
    } else {
        int i = t - EB;
        if (i >= n) return;
        const int* cnt = s ? cnt1 : cnt0;
        const int* off = s ? off1 : off0;
        int p = off[i] + cnt[i], pe = off[i + 1];
        float di = dinv[i];
        rec[p++] = make_uint2((unsigned)i,
                              ((unsigned)f2h(di * di) << 16) | 0x3C00u);  // w2=1
        for (; p < pe; ++p) rec[p] = make_uint2(0u, 0u);
    }
}

// ---------------- dtype conversions ----------------

// xc[i][k] (bf16, KP cols): k<F -> x, k<KC -> d2an, else 0. 8 elems/thread.
__global__ void k_xcv(const float* __restrict__ x, const float* __restrict__ pe,
                      unsigned short* __restrict__ xc, int n, int F, int PEd,
                      int KC, int KP) {
    const int CH = KP >> 3;                       // chunks per row
    int idx = blockIdx.x * 256 + threadIdx.x;
    if (idx >= n * CH) return;
    int i = idx / CH, c = idx - i * CH;
    int k = c << 3;
    uint4 o;
    if (k + 8 <= F) {
        const float4* px = (const float4*)(x + (size_t)i * F + k);
        float4 v0 = px[0];
        float4 v1 = px[1];
        o.x = (unsigned)f2b(v0.x) | ((unsigned)f2b(v0.y) << 16);
        o.y = (unsigned)f2b(v0.z) | ((unsigned)f2b(v0.w) << 16);
        o.z = (unsigned)f2b(v1.x) | ((unsigned)f2b(v1.y) << 16);
        o.w = (unsigned)f2b(v1.z) | ((unsigned)f2b(v1.w) << 16);
    } else if (k < KC) {
        const float* pp = pe + (size_t)i * PEd + (k - F);
        int rem = KC - k;
        float e0 = pp[0];
        float e1 = (1 < rem) ? pp[1] : 0.f;
        float e2 = (2 < rem) ? pp[2] : 0.f;
        float e3 = (3 < rem) ? pp[3] : 0.f;
        float e4 = (4 < rem) ? pp[4] : 0.f;
        float e5 = (5 < rem) ? pp[5] : 0.f;
        float e6 = (6 < rem) ? pp[6] : 0.f;
        float e7 = (7 < rem) ? pp[7] : 0.f;
        o.x = (unsigned)f2b(e0) | ((unsigned)f2b(e1) << 16);
        o.y = (unsigned)f2b(e2) | ((unsigned)f2b(e3) << 16);
        o.z = (unsigned)f2b(e4) | ((unsigned)f2b(e5) << 16);
        o.w = (unsigned)f2b(e6) | ((unsigned)f2b(e7) << 16);
    } else {
        o.x = o.y = o.z = o.w = 0u;
    }
    *(uint4*)(xc + (size_t)idx * 8) = o;
}

// weight conversions (row-major K):
//   seg 0/1: Wn [F][KC] f32 -> [F][KP] bf16 zero-padded
//   seg 2..5: [Wa|Wb] pairs -> [F][512] bf16 plain concat
__global__ void k_wall(const float* __restrict__ Wn1, const float* __restrict__ Wn2,
                       const float* __restrict__ W11, const float* __restrict__ W12,
                       const float* __restrict__ W21, const float* __restrict__ W22,
                       const float* __restrict__ W31, const float* __restrict__ W32,
                       const float* __restrict__ W41, const float* __restrict__ W42,
                       unsigned short* __restrict__ wn0c, unsigned short* __restrict__ wn1c,
                       unsigned short* __restrict__ wc0, unsigned short* __restrict__ wc1,
                       unsigned short* __restrict__ wc2, unsigned short* __restrict__ wc3,
                       int F, int KC, int KP) {
    int idx = blockIdx.x * 256 + threadIdx.x;
    int npad = F * KP;
    if (idx < 2 * npad) {
        const float* W = (idx < npad) ? Wn1 : Wn2;
        unsigned short* Wc = (idx < npad) ? wn0c : wn1c;
        int t = (idx < npad) ? idx : idx - npad;
        int o = t / KP, k = t - o * KP;
        Wc[t] = f2b(k < KC ? W[(size_t)o * KC + k] : 0.0f);
        return;
    }
    int t = idx - 2 * npad;
    int seg = F * 512;
    if (t >= 4 * seg) return;
    int which = t / seg;
    int r = t - which * seg;
    const float* Wa = (which == 0) ? W11 : (which == 1) ? W21 : (which == 2) ? W31 : W41;
    const float* Wb = (which == 0) ? W12 : (which == 1) ? W22 : (which == 2) ? W32 : W42;
    unsigned short* Wc = (which == 0) ? wc0 : (which == 1) ? wc1 : (which == 2) ? wc2 : wc3;
    int o = r >> 9, k = r & 511;
    float v = (k < 256) ? Wa[(size_t)o * 256 + k] : Wb[(size_t)o * 256 + (k - 256)];
    Wc[r] = f2b(v);
}

// ---------------- CSR gather-aggregation v5 (software-pipelined) ----------------
// One wave per node. Lanes 0-31: even records, 32-63: odd records; dwordx4
// gathers (16B/lane). Depth-1 pipeline: prefetch next record-quad + issue its
// gathers before consuming the current quad's FMAs (counted vmcnt overlap).
// No local arrays anywhere (R7 lesson). Output A[i] = [a1(256)|a2(256)] bf16.

#define AGG_SLOT(g, wsel)                                                     \
    do {                                                                      \
        float w1 = h2f((unsigned short)((wsel) >> 16));                       \
        float w2 = h2f((unsigned short)((wsel) & 0xFFFFu));                   \
        f32x2 w1v = {w1, w1};                                                 \
        f32x2 w2v = {w2, w2};                                                 \
        f32x2 v;                                                              \
        v.x = __uint_as_float((g).x << 16);                                   \
        v.y = __uint_as_float((g).x & 0xFFFF0000u);                           \
        c1a = __builtin_elementwise_fma(w1v, v, c1a);                         \
        c2a = __builtin_elementwise_fma(w2v, v, c2a);                         \
        v.x = __uint_as_float((g).y << 16);                                   \
        v.y = __uint_as_float((g).y & 0xFFFF0000u);                           \
        c1b = __builtin_elementwise_fma(w1v, v, c1b);                         \
        c2b = __builtin_elementwise_fma(w2v, v, c2b);                         \
        v.x = __uint_as_float((g).z << 16);                                   \
        v.y = __uint_as_float((g).z & 0xFFFF0000u);                           \
        c1c = __builtin_elementwise_fma(w1v, v, c1c);                         \
        c2c = __builtin_elementwise_fma(w2v, v, c2c);                         \
        v.x = __uint_as_float((g).w << 16);                                   \
        v.y = __uint_as_float((g).w & 0xFFFF0000u);                           \
        c1d = __builtin_elementwise_fma(w1v, v, c1d);                         \
        c2d = __builtin_elementwise_fma(w2v, v, c2d);                         \
    } while (0)

#define SELG(q, wsel, g)                                                      \
    do {                                                                      \
        unsigned _s = hi ? (q).z : (q).x;                                     \
        wsel = hi ? (q).w : (q).y;                                            \
        g = *(const uint4*)(Xb + ((_s << 9) | loff));                         \
    } while (0)

__global__ __launch_bounds__(256) void k_agg(
    const unsigned short* __restrict__ X0, const unsigned short* __restrict__ X1,
    const int* __restrict__ off0, const int* __restrict__ off1,
    const uint2* __restrict__ rec0, const uint2* __restrict__ rec1,
    unsigned short* __restrict__ A0, unsigned short* __restrict__ A1, int n) {
    const int s = blockIdx.y;
    const char* Xb = (const char*)(s ? X1 : X0);
    const int* off = s ? off1 : off0;
    const uint2* rec = s ? rec1 : rec0;
    unsigned short* A = s ? A1 : A0;

    const int gw = (blockIdx.x * 256 + threadIdx.x) >> 6;
    const int lane = threadIdx.x & 63;
    if (gw >= n) return;

    const int e0 = __builtin_amdgcn_readfirstlane(off[gw]);
    const int e1 = __builtin_amdgcn_readfirstlane(off[gw + 1]);
    const bool hi = lane >= 32;
    const unsigned loff = (unsigned)(lane & 31) << 4;   // 16B chunk within row

    f32x2 c1a = {0.f, 0.f}, c1b = {0.f, 0.f}, c1c = {0.f, 0.f}, c1d = {0.f, 0.f};
    f32x2 c2a = {0.f, 0.f}, c2b = {0.f, 0.f}, c2c = {0.f, 0.f}, c2d = {0.f, 0.f};

    const uint4* recq = (const uint4*)(rec + e0);   // 1 uint4 = 2 records
    const int nit = (e1 - e0) >> 3;                 // 8 records / iter, >= 1

    // prologue: quad 0
    uint4 qa = recq[0], qb = recq[1], qc = recq[2], qd = recq[3];
    unsigned wa, wb, wcs, wd;
    uint4 ga, gb, gc, gd;
    SELG(qa, wa, ga);
    SELG(qb, wb, gb);
    SELG(qc, wcs, gc);
    SELG(qd, wd, gd);

    #pragma unroll 2
    for (int it = 0; it < nit - 1; ++it) {
        const uint4* nq = recq + (size_t)(it + 1) * 4;
        uint4 na = nq[0], nb = nq[1], nc = nq[2], nd = nq[3];
        unsigned nwa, nwb, nwc, nwd;
        uint4 nga, ngb, ngc, ngd;
        SELG(na, nwa, nga);
        SELG(nb, nwb, ngb);
        SELG(nc, nwc, ngc);
        SELG(nd, nwd, ngd);
        AGG_SLOT(ga, wa);
        AGG_SLOT(gb, wb);
        AGG_SLOT(gc, wcs);
        AGG_SLOT(gd, wd);
        wa = nwa; wb = nwb; wcs = nwc; wd = nwd;
        ga = nga; gb = ngb; gc = ngc; gd = ngd;
    }
    AGG_SLOT(ga, wa);
    AGG_SLOT(gb, wb);
    AGG_SLOT(gc, wcs);
    AGG_SLOT(gd, wd);

    // combine halves (lane L and L^32 hold the same 8 feats over disjoint edges)
    float u0 = c1a.x + __shfl_xor(c1a.x, 32);
    float u1 = c1a.y + __shfl_xor(c1a.y, 32);
    float u2 = c1b.x + __shfl_xor(c1b.x, 32);
    float u3 = c1b.y + __shfl_xor(c1b.y, 32);
    float u4 = c1c.x + __shfl_xor(c1c.x, 32);
    float u5 = c1c.y + __shfl_xor(c1c.y, 32);
    float u6 = c1d.x + __shfl_xor(c1d.x, 32);
    float u7 = c1d.y + __shfl_xor(c1d.y, 32);
    float t0 = c2a.x + __shfl_xor(c2a.x, 32);
    float t1 = c2a.y + __shfl_xor(c2a.y, 32);
    float t2 = c2b.x + __shfl_xor(c2b.x, 32);
    float t3 = c2b.y + __shfl_xor(c2b.y, 32);
    float t4 = c2c.x + __shfl_xor(c2c.x, 32);
    float t5 = c2c.y + __shfl_xor(c2c.y, 32);
    float t6 = c2d.x + __shfl_xor(c2d.x, 32);
    float t7 = c2d.y + __shfl_xor(c2d.y, 32);

    float s0 = hi ? t0 : u0;
    float s1 = hi ? t1 : u1;
    float s2 = hi ? t2 : u2;
    float s3 = hi ? t3 : u3;
    float s4 = hi ? t4 : u4;
    float s5 = hi ? t5 : u5;
    float s6 = hi ? t6 : u6;
    float s7 = hi ? t7 : u7;
    uint4 o;
    o.x = (unsigned)f2b(s0) | ((unsigned)f2b(s1) << 16);
    o.y = (unsigned)f2b(s2) | ((unsigned)f2b(s3) << 16);
    o.z = (unsigned)f2b(s4) | ((unsigned)f2b(s5) << 16);
    o.w = (unsigned)f2b(s6) | ((unsigned)f2b(s7) << 16);
    *(uint4*)(A + (size_t)gw * 512 + (hi ? 256 : 0) + ((lane & 31) << 3)) = o;
}

// ---------------- bf16 MFMA GEMM kernels ----------------
#define GLL(g, l) \
    __builtin_amdgcn_global_load_lds((__attribute__((address_space(1))) void*)(g), \
                                     (__attribute__((address_space(3))) void*)(l), 16, 0, 0)

// node-transform GEMM: C[M][Nc] = A[M][K] @ B[Nc][K]^T, bf16 out, z selects B/out.
__global__ __launch_bounds__(256) void gemm_bt(
    const unsigned short* __restrict__ A,
    const unsigned short* __restrict__ B0, const unsigned short* __restrict__ B1,
    int M, int K, int Nc,
    unsigned short* __restrict__ outH0, unsigned short* __restrict__ outH1) {
    const unsigned short* B = blockIdx.z ? B1 : B0;
    unsigned short* outH = blockIdx.z ? outH1 : outH0;

    __shared__ __align__(16) unsigned short sA[128 * 32];
    __shared__ __align__(16) unsigned short sB[128 * 32];
    const int tid = threadIdx.x;
    const int lane = tid & 63;
    const int wave = tid >> 6;
    const int bm = blockIdx.x * 128;
    const int bn = blockIdx.y * 128;

    const int r0 = wave * 32 + (lane >> 2);
    const int kcol = (lane & 3) * 8;
    const int ga0 = min(bm + r0, M - 1);
    const int ga1 = min(bm + r0 + 16, M - 1);
    const int gb0 = min(bn + r0, Nc - 1);
    const int gb1 = min(bn + r0 + 16, Nc - 1);
    const unsigned short* pa0 = A + (size_t)ga0 * K + kcol;
    const unsigned short* pa1 = A + (size_t)ga1 * K + kcol;
    const unsigned short* pb0 = B + (size_t)gb0 * K + kcol;
    const unsigned short* pb1 = B + (size_t)gb1 * K + kcol;
    unsigned short* la0 = &sA[wave * 1024];
    unsigned short* la1 = &sA[wave * 1024 + 512];
    unsigned short* lb0 = &sB[wave * 1024];
    unsigned short* lb1 = &sB[wave * 1024 + 512];

    floatx4 acc[4][4];
    #pragma unroll
    for (int i = 0; i < 4; i++)
        #pragma unroll
        for (int j = 0; j < 4; j++) acc[i][j] = (floatx4){0.f, 0.f, 0.f, 0.f};

    const int mbase = (wave & 1) * 64 + (lane & 15);
    const int nbase = (wave >> 1) * 64 + (lane & 15);
    const int koff = (lane >> 4) * 8;

    for (int kk = 0; kk < K; kk += 32) {
        GLL(pa0 + kk, la0);
        GLL(pa1 + kk, la1);
        GLL(pb0 + kk, lb0);
        GLL(pb1 + kk, lb1);
        __syncthreads();
        bf16x8 af[4], bf[4];
        #pragma unroll
        for (int mi = 0; mi < 4; mi++)
            af[mi] = *(const bf16x8*)&sA[(mbase + mi * 16) * 32 + koff];
        #pragma unroll
        for (int ni = 0; ni < 4; ni++)
            bf[ni] = *(const bf16x8*)&sB[(nbase + ni * 16) * 32 + koff];
        #pragma unroll
        for (int mi = 0; mi < 4; mi++)
            #pragma unroll
            for (int ni = 0; ni < 4; ni++)
                acc[mi][ni] = __builtin_amdgcn_mfma_f32_16x16x32_bf16(
                    af[mi], bf[ni], acc[mi][ni], 0, 0, 0);
        __syncthreads();
    }

    const int crow = bm + (wave & 1) * 64 + (lane >> 4) * 4;
    const int ccol = bn + (wave >> 1) * 64 + (lane & 15);
    #pragma unroll
    for (int mi = 0; mi < 4; mi++)
        #pragma unroll
        for (int ni = 0; ni < 4; ni++)
            #pragma unroll
            for (int r = 0; r < 4; r++) {
                int row = crow + mi * 16 + r;
                if (row >= M) continue;
                int col = ccol + ni * 16;
                outH[(size_t)row * Nc + col] = f2b(acc[mi][ni][r]);
            }
}

// dual GEMM: C = 0.5*relu(A0@B0^T) + 0.5*relu(A1@B1^T); out f32 or bf16.
__global__ __launch_bounds__(256) void gemm_dual(
    const unsigned short* __restrict__ A0, const unsigned short* __restrict__ B0,
    const unsigned short* __restrict__ A1, const unsigned short* __restrict__ B1,
    int M, int K, int Nc,
    float* __restrict__ outF, unsigned short* __restrict__ outH, float alpha) {
    __shared__ __align__(16) unsigned short sA[128 * 32];
    __shared__ __align__(16) unsigned short sB[128 * 32];
    const int tid = threadIdx.x;
    const int lane = tid & 63;
    const int wave = tid >> 6;
    const int bm = blockIdx.x * 128;
    const int bn = blockIdx.y * 128;

    const int r0 = wave * 32 + (lane >> 2);
    const int kcol = (lane & 3) * 8;
    const int ga0 = min(bm + r0, M - 1);
    const int ga1 = min(bm + r0 + 16, M - 1);
    const int gb0 = min(bn + r0, Nc - 1);
    const int gb1 = min(bn + r0 + 16, Nc - 1);
    unsigned short* la0 = &sA[wave * 1024];
    unsigned short* la1 = &sA[wave * 1024 + 512];
    unsigned short* lb0 = &sB[wave * 1024];
    unsigned short* lb1 = &sB[wave * 1024 + 512];

    const int mbase = (wave & 1) * 64 + (lane & 15);
    const int nbase = (wave >> 1) * 64 + (lane & 15);
    const int koff = (lane >> 4) * 8;

    floatx4 acc[4][4], res[4][4];

    #pragma unroll
    for (int pass = 0; pass < 2; pass++) {
        const unsigned short* A = pass ? A1 : A0;
        const unsigned short* B = pass ? B1 : B0;
        const unsigned short* pa0 = A + (size_t)ga0 * K + kcol;
        const unsigned short* pa1 = A + (size_t)ga1 * K + kcol;
        const unsigned short* pb0 = B + (size_t)gb0 * K + kcol;
        const unsigned short* pb1 = B + (size_t)gb1 * K + kcol;
        #pragma unroll
        for (int i = 0; i < 4; i++)
            #pragma unroll
            for (int j = 0; j < 4; j++) acc[i][j] = (floatx4){0.f, 0.f, 0.f, 0.f};

        for (int kk = 0; kk < K; kk += 32) {
            GLL(pa0 + kk, la0);
            GLL(pa1 + kk, la1);
            GLL(pb0 + kk, lb0);
            GLL(pb1 + kk, lb1);
            __syncthreads();
            bf16x8 af[4], bf[4];
            #pragma unroll
            for (int mi = 0; mi < 4; mi++)
                af[mi] = *(const bf16x8*)&sA[(mbase + mi * 16) * 32 + koff];
            #pragma unroll
            for (int ni = 0; ni < 4; ni++)
                bf[ni] = *(const bf16x8*)&sB[(nbase + ni * 16) * 32 + koff];
            #pragma unroll
            for (int mi = 0; mi < 4; mi++)
                #pragma unroll
                for (int ni = 0; ni < 4; ni++)
                    acc[mi][ni] = __builtin_amdgcn_mfma_f32_16x16x32_bf16(
                        af[mi], bf[ni], acc[mi][ni], 0, 0, 0);
            __syncthreads();
        }
        if (pass == 0) {
            #pragma unroll
            for (int mi = 0; mi < 4; mi++)
                #pragma unroll
                for (int ni = 0; ni < 4; ni++)
                    #pragma unroll
                    for (int r = 0; r < 4; r++)
                        res[mi][ni][r] = fmaxf(acc[mi][ni][r], 0.0f);
        }
    }

    const int crow = bm + (wave & 1) * 64 + (lane >> 4) * 4;
    const int ccol = bn + (wave >> 1) * 64 + (lane & 15);
    #pragma unroll
    for (int mi = 0; mi < 4; mi++)
        #pragma unroll
        for (int ni = 0; ni < 4; ni++)
            #pragma unroll
            for (int r = 0; r < 4; r++) {
                int row = crow + mi * 16 + r;
                if (row >= M) continue;
                int col = ccol + ni * 16;
                float v = alpha * (res[mi][ni][r] + fmaxf(acc[mi][ni][r], 0.0f));
                size_t idx = (size_t)row * Nc + col;
                if (outF) outF[idx] = v;
                else      outH[idx] = f2b(v);
            }
}

// ---------------- host orchestration ----------------

extern "C" void kernel_launch(void* const* d_in, const int* in_sizes, int n_in,
                              void* d_out, int out_size, void* d_ws, size_t ws_size,
                              hipStream_t stream) {
    const int F = 256;
    const int N = in_sizes[0] / F;
    const int PEd = in_sizes[1] / N;          // 98
    const int E = in_sizes[2] / 2;            // 800000
    const int KC = F + PEd;                   // 354
    const int KP = (KC + 31) & ~31;           // 384

    const float* x   = (const float*)d_in[0];
    const float* pe  = (const float*)d_in[1];
    const int*   ei0 = (const int*)d_in[2];
    const float* ea0 = (const float*)d_in[3];
    const int*   ei1 = (const int*)d_in[4];
    const float* ea1 = (const float*)d_in[5];
    const float* Wn1 = (const float*)d_in[6];
    const float* Wn2 = (const float*)d_in[7];
    const float* W11 = (const float*)d_in[8];
    const float* W12 = (const float*)d_in[9];
    const float* W21 = (const float*)d_in[10];
    const float* W22 = (const float*)d_in[11];
    const float* W31 = (const float*)d_in[12];
    const float* W32 = (const float*)d_in[13];
    const float* W41 = (const float*)d_in[14];
    const float* W42 = (const float*)d_in[15];
    float* out = (float*)d_out;

    char* p = (char*)d_ws;
    auto alloc = [&](size_t b) -> char* {
        char* r = p;
        p += (b + 255) & ~(size_t)255;
        return r;
    };
    int*   cnt0  = (int*)alloc((size_t)N * 4);
    int*   cnt1  = (int*)alloc((size_t)N * 4);
    int*   off0  = (int*)alloc((size_t)(N + 1) * 4);
    int*   off1  = (int*)alloc((size_t)(N + 1) * 4);
    int*   cur0  = (int*)alloc((size_t)N * 4);
    int*   cur1  = (int*)alloc((size_t)N * 4);
    float* dinv0 = (float*)alloc((size_t)N * 4);
    float* dinv1 = (float*)alloc((size_t)N * 4);
    int*   bs0   = (int*)alloc(64 * 4);
    int*   bs1   = (int*)alloc(64 * 4);
    uint2* rec0  = (uint2*)alloc(((size_t)E + 8ull * N) * 8);   // padded CSR
    uint2* rec1  = (uint2*)alloc(((size_t)E + 8ull * N) * 8);
    unsigned short* wn0c = (unsigned short*)alloc((size_t)F * KP * 2);
    unsigned short* wn1c = (unsigned short*)alloc((size_t)F * KP * 2);
    unsigned short* wc0  = (unsigned short*)alloc((size_t)F * 512 * 2);
    unsigned short* wc1  = (unsigned short*)alloc((size_t)F * 512 * 2);
    unsigned short* wc2  = (unsigned short*)alloc((size_t)F * 512 * 2);
    unsigned short* wc3  = (unsigned short*)alloc((size_t)F * 512 * 2);
    unsigned short* xa   = (unsigned short*)alloc((size_t)N * 512 * 2);  // xa|xb
    unsigned short* xb   = xa + (size_t)N * 256;
    unsigned short* h    = (unsigned short*)alloc((size_t)N * F * 2);
    unsigned short* a12  = (unsigned short*)alloc((size_t)N * 512 * 2);
    unsigned short* xc   = a12;                  // dead after node transforms
    unsigned short* a12bL1 = (unsigned short*)d_out;  // N*512 bf16 == out_size f32
    unsigned short* a12bL2 = xa;                 // xa|xb dead after layer-1 agg

    const int B = 256;
    const int gE = (E + B - 1) / B;
    const int gN = (N + B - 1) / B;
    const int gW = (N + 3) / 4;                  // 4 waves (nodes) per block
    const int nb = (N + 1023) / 1024;            // scan blocks
    dim3 gemm_grid((N + 127) / 128, 2);
    dim3 gemm_grid2((N + 127) / 128, 2, 2);

    // 1. degree / dinv / padded CSR (self-loop record included)
    hipMemsetAsync(cnt0, 0, (size_t)N * 4, stream);
    hipMemsetAsync(cnt1, 0, (size_t)N * 4, stream);
    k_cnt2<<<dim3(gE, 2), B, 0, stream>>>(ei0 + E, ei1 + E, E, cnt0, cnt1);
    k_scanA<<<dim3(nb, 2), 1024, 0, stream>>>(cnt0, cnt1, off0, off1, bs0, bs1, N);
    k_scanB<<<dim3(1, 2), 64, 0, stream>>>(bs0, bs1, nb);
    k_scanC<<<dim3(nb, 2), 1024, 0, stream>>>(bs0, bs1, cnt0, cnt1, off0, off1,
                                              dinv0, dinv1, cur0, cur1, N);
    k_fillpad<<<dim3(gE + gN, 2), B, 0, stream>>>(
        ei0, ea0, ei1, ea1, E, gE * B, cnt0, cnt1, off0, off1,
        dinv0, dinv1, cur0, cur1, rec0, rec1, N);

    // 2. bf16 conversions
    k_xcv<<<((size_t)N * (KP / 8) + B - 1) / B, B, 0, stream>>>(
        x, pe, xc, N, F, PEd, KC, KP);
    {
        int tot = 2 * F * KP + 4 * F * 512;
        k_wall<<<(tot + B - 1) / B, B, 0, stream>>>(Wn1, Wn2, W11, W12, W21, W22,
                                                    W31, W32, W41, W42,
                                                    wn0c, wn1c, wc0, wc1, wc2, wc3,
                                                    F, KC, KP);
    }

    // 3. node transforms (both via blockIdx.z) -> xa, xb  [row-major N x 256]
    gemm_bt<<<gemm_grid2, B, 0, stream>>>(xc, wn0c, wn1c, N, KP, F, xa, xb);

    // 4. layer 1: both aggs in one dispatch; then dual GEMM -> h (bf16)
    k_agg<<<dim3(gW, 2), B, 0, stream>>>(xa, xb, off0, off1, rec0, rec1,
                                         a12, a12bL1, N);
    gemm_dual<<<gemm_grid, B, 0, stream>>>(a12, wc0, a12bL1, wc1, N, 512, F,
                                           nullptr, h, 0.5f);

    // 5. layer 2: both aggs in one dispatch; then dual GEMM -> out (f32)
    k_agg<<<dim3(gW, 2), B, 0, stream>>>(h, h, off0, off1, rec0, rec1,
                                         a12, a12bL2, N);
    gemm_dual<<<gemm_grid, B, 0, stream>>>(a12, wc2, a12bL2, wc3, N, 512, F,
                                           out, nullptr, 0.5f);
}

// Round 4
// 707.917 us; speedup vs baseline: 1.3055x; 1.0248x over previous
//
#include <hip/hip_runtime.h>

// ---------------------------------------------------------------------------
// GraphTrajSimEncoder on MI355X — round 10.
// R9 post-mortem: depth-1 pipeline = zero effect (TLP already covers it);
// k_agg plateau ~124us tracks L2-miss gather traffic, not scheduling. v2-style
// (64-lane/record, occ 74%) was fastest of 3 variants. R10:
//  - k_agg v6: v2 structure + x4 padding (records/node 24->20, -17% traffic),
//    uint4 record loads, pk-fma, no cross-half combine epilogue
//  - k_cnt2+k_xcv+k_wall fused into one segmented dispatch (k_front)
//  - single memset for cnt0|cnt1
// ---------------------------------------------------------------------------

using bf16x8  = __attribute__((ext_vector_type(8))) __bf16;
using floatx4 = __attribute__((ext_vector_type(4))) float;
using f32x2   = __attribute__((ext_vector_type(2))) float;

__device__ __forceinline__ unsigned short f2b(float f) {
    unsigned u = __float_as_uint(f);
    return (unsigned short)((u + 0x7FFFu + ((u >> 16) & 1u)) >> 16);
}
__device__ __forceinline__ unsigned short f2h(float f) {
    _Float16 h = (_Float16)f;
    return __builtin_bit_cast(unsigned short, h);
}
__device__ __forceinline__ float h2f(unsigned short u) {
    return (float)__builtin_bit_cast(_Float16, u);
}

// ---------------- fused front kernel ----------------
// segment 0: [0, E)            set-0 degree count atomics
// segment 1: [E, 2E)           set-1 degree count atomics
// segment 2: [2E, 2E+NXC)      xc bf16 conversion, 8 elems/thread
// segment 3: [.., +TOTW)       weight conversions
__global__ void k_front(
    const int* __restrict__ col0, const int* __restrict__ col1, int E,
    int* __restrict__ cnt0, int* __restrict__ cnt1,
    const float* __restrict__ x, const float* __restrict__ pe,
    unsigned short* __restrict__ xc,
    const float* __restrict__ Wn1, const float* __restrict__ Wn2,
    const float* __restrict__ W11, const float* __restrict__ W12,
    const float* __restrict__ W21, const float* __restrict__ W22,
    const float* __restrict__ W31, const float* __restrict__ W32,
    const float* __restrict__ W41, const float* __restrict__ W42,
    unsigned short* __restrict__ wn0c, unsigned short* __restrict__ wn1c,
    unsigned short* __restrict__ wc0, unsigned short* __restrict__ wc1,
    unsigned short* __restrict__ wc2, unsigned short* __restrict__ wc3,
    int n, int F, int PEd, int KC, int KP) {
    int idx = blockIdx.x * 256 + threadIdx.x;
    if (idx < E) { atomicAdd(&cnt0[col0[idx]], 1); return; }
    idx -= E;
    if (idx < E) { atomicAdd(&cnt1[col1[idx]], 1); return; }
    idx -= E;
    const int CH = KP >> 3;
    const int NXC = n * CH;
    if (idx < NXC) {
        int i = idx / CH, c = idx - i * CH;
        int k = c << 3;
        uint4 o;
        if (k + 8 <= F) {
            const float4* px = (const float4*)(x + (size_t)i * F + k);
            float4 v0 = px[0];
            float4 v1 = px[1];
            o.x = (unsigned)f2b(v0.x) | ((unsigned)f2b(v0.y) << 16);
            o.y = (unsigned)f2b(v0.z) | ((unsigned)f2b(v0.w) << 16);
            o.z = (unsigned)f2b(v1.x) | ((unsigned)f2b(v1.y) << 16);
            o.w = (unsigned)f2b(v1.z) | ((unsigned)f2b(v1.w) << 16);
        } else if (k < KC) {
            const float* pp = pe + (size_t)i * PEd + (k - F);
            int rem = KC - k;
            float e0 = pp[0];
            float e1 = (1 < rem) ? pp[1] : 0.f;
            float e2 = (2 < rem) ? pp[2] : 0.f;
            float e3 = (3 < rem) ? pp[3] : 0.f;
            float e4 = (4 < rem) ? pp[4] : 0.f;
            float e5 = (5 < rem) ? pp[5] : 0.f;
            float e6 = (6 < rem) ? pp[6] : 0.f;
            float e7 = (7 < rem) ? pp[7] : 0.f;
            o.x = (unsigned)f2b(e0) | ((unsigned)f2b(e1) << 16);
            o.y = (unsigned)f2b(e2) | ((unsigned)f2b(e3) << 16);
            o.z = (unsigned)f2b(e4) | ((unsigned)f2b(e5) << 16);
            o.w = (unsigned)f2b(e6) | ((unsigned)f2b(e7) << 16);
        } else {
            o.x = o.y = o.z = o.w = 0u;
        }
        *(uint4*)(xc + (size_t)idx * 8) = o;
        return;
    }
    idx -= NXC;
    int npad = F * KP;
    if (idx < 2 * npad) {
        const float* W = (idx < npad) ? Wn1 : Wn2;
        unsigned short* Wc = (idx < npad) ? wn0c : wn1c;
        int t = (idx < npad) ? idx : idx - npad;
        int o = t / KP, k = t - o * KP;
        Wc[t] = f2b(k < KC ? W[(size_t)o * KC + k] : 0.0f);
        return;
    }
    int t = idx - 2 * npad;
    int seg = F * 512;
    if (t >= 4 * seg) return;
    int which = t / seg;
    int r = t - which * seg;
    const float* Wa = (which == 0) ? W11 : (which == 1) ? W21 : (which == 2) ? W31 : W41;
    const float* Wb = (which == 0) ? W12 : (which == 1) ? W22 : (which == 2) ? W32 : W42;
    unsigned short* Wc = (which == 0) ? wc0 : (which == 1) ? wc1 : (which == 2) ? wc2 : wc3;
    int o = r >> 9, k = r & 511;
    float v = (k < 256) ? Wa[(size_t)o * 256 + k] : Wb[(size_t)o * 256 + (k - 256)];
    Wc[r] = f2b(v);
}

// ---------------- scans ----------------
// Pad per node = (cnt + 1 self) rounded up to 4.
// Phase A: per-block (1024 elems) inclusive scan -> off[i+1] (local), block sum.
__global__ __launch_bounds__(1024) void k_scanA(
    const int* __restrict__ cnt0, const int* __restrict__ cnt1,
    int* __restrict__ off0, int* __restrict__ off1,
    int* __restrict__ bs0, int* __restrict__ bs1, int n) {
    const int* cnt = blockIdx.y ? cnt1 : cnt0;
    int* off = blockIdx.y ? off1 : off0;
    int* bs  = blockIdx.y ? bs1 : bs0;
    __shared__ int wsum[16];
    __shared__ int wpre[16];
    const int t = threadIdx.x;
    const int lane = t & 63;
    const int w = t >> 6;
    const int i = blockIdx.x * 1024 + t;
    int v = (i < n) ? ((cnt[i] + 4) & ~3) : 0;   // cnt + self, padded to x4
    #pragma unroll
    for (int d = 1; d < 64; d <<= 1) {
        int u = __shfl_up(v, d, 64);
        if (lane >= d) v += u;
    }
    if (lane == 63) wsum[w] = v;
    __syncthreads();
    if (t < 16) {
        int s2 = wsum[t];
        #pragma unroll
        for (int d = 1; d < 16; d <<= 1) {
            int u = __shfl_up(s2, d, 16);
            if (t >= d) s2 += u;
        }
        wpre[t] = s2;
    }
    __syncthreads();
    int incl = v + (w > 0 ? wpre[w - 1] : 0);
    if (i < n) off[i + 1] = incl;
    if (t == 1023) bs[blockIdx.x] = incl;
}

// Phase B: one wave scans the (<=64) block sums -> exclusive prefixes in place.
__global__ void k_scanB(int* __restrict__ bs0, int* __restrict__ bs1, int nb) {
    int* bs = blockIdx.y ? bs1 : bs0;
    const int t = threadIdx.x;       // 64 threads
    int v = (t < nb) ? bs[t] : 0;
    int orig = v;
    #pragma unroll
    for (int d = 1; d < 64; d <<= 1) {
        int u = __shfl_up(v, d, 64);
        if (t >= d) v += u;
    }
    if (t < nb) bs[t] = v - orig;    // exclusive
}

// Phase C: add block prefix; off[0]=0; fused prep: cur[i], dinv[i].
__global__ __launch_bounds__(1024) void k_scanC(
    const int* __restrict__ bs0, const int* __restrict__ bs1,
    const int* __restrict__ cnt0, const int* __restrict__ cnt1,
    int* __restrict__ off0, int* __restrict__ off1,
    float* __restrict__ dinv0, float* __restrict__ dinv1,
    int* __restrict__ cur0, int* __restrict__ cur1, int n) {
    int* off = blockIdx.y ? off1 : off0;
    const int* bs = blockIdx.y ? bs1 : bs0;
    const int* cnt = blockIdx.y ? cnt1 : cnt0;
    float* dinv = blockIdx.y ? dinv1 : dinv0;
    int* cur = blockIdx.y ? cur1 : cur0;
    const int i = blockIdx.x * 1024 + threadIdx.x;
    if (i == 0) off[0] = 0;
    if (i < n) {
        int ci = cnt[i];
        int o = off[i + 1] + (blockIdx.x > 0 ? bs[blockIdx.x] : 0);
        off[i + 1] = o;
        cur[i] = o - ((ci + 4) & ~3);
        dinv[i] = rsqrtf((float)(ci + 1));
    }
}

// Fused CSR fill + self-loop/pad. Threads [0, EB) fill edges; [EB, EB+n) pad.
// Edge record: (src:u32, (fp16 w1)<<16 | fp16 w2). Self: w1=dinv^2, w2=1.
__global__ void k_fillpad(
    const int* __restrict__ ei0, const float* __restrict__ ea0,
    const int* __restrict__ ei1, const float* __restrict__ ea1,
    int E, int EB,
    const int* __restrict__ cnt0, const int* __restrict__ cnt1,
    const int* __restrict__ off0, const int* __restrict__ off1,
    const float* __restrict__ dinv0, const float* __restrict__ dinv1,
    int* __restrict__ cur0, int* __restrict__ cur1,
    uint2* __restrict__ rec0, uint2* __restrict__ rec1, int n) {
    const int s = blockIdx.y;
    const float* dinv = s ? dinv1 : dinv0;
    uint2* rec = s ? rec1 : rec0;
    int t = blockIdx.x * 256 + threadIdx.x;
    if (t < EB) {
        int e = t;
        if (e >= E) return;
        const int* ei = s ? ei1 : ei0;
        const float* ea = s ? ea1 : ea0;
        int* cur = s ? cur1 : cur0;
        int r = ei[e];          // source
        int c = ei[E + e];      // target
        float a = ea[e];
        float w2 = (a > 0.0f) ? fminf(rsqrtf(a), 1.0f) : 0.0f;
        float w1 = dinv[r] * dinv[c];
        int p = atomicAdd(&cur[c], 1);
        rec[p] = make_uint2((unsigned)r,
                            ((unsigned)f2h(w1) << 16) | (unsigned)f2h(w2));
    } else {
        int i = t - EB;
        if (i >= n) return;
        const int* cnt = s ? cnt1 : cnt0;
        const int* off = s ? off1 : off0;
        int p = off[i] + cnt[i], pe = off[i + 1];
        float di = dinv[i];
        rec[p++] = make_uint2((unsigned)i,
                              ((unsigned)f2h(di * di) << 16) | 0x3C00u);  // w2=1
        for (; p < pe; ++p) rec[p] = make_uint2(0u, 0u);
    }
}

// ---------------- CSR gather-aggregation v6 ----------------
// One wave per node, one 64-lane gather per record (8B/lane = 512B row).
// x4 CSR padding (was x8): avg records/node 24 -> 20. Records loaded as
// uint4 pairs (4 records / 2 loads). Packed f32 FMA. Self loop is a record.
// No local arrays (R7 lesson), no pipeline (R9 lesson: TLP covers it).
// Output A[i] = [a1(256) | a2(256)] bf16.

#define AGG4(g, wsel)                                                         \
    do {                                                                      \
        float w1 = h2f((unsigned short)((wsel) >> 16));                       \
        float w2 = h2f((unsigned short)((wsel) & 0xFFFFu));                   \
        f32x2 w1v = {w1, w1};                                                 \
        f32x2 w2v = {w2, w2};                                                 \
        f32x2 v;                                                              \
        v.x = __uint_as_float((g).x << 16);                                   \
        v.y = __uint_as_float((g).x & 0xFFFF0000u);                           \
        c1a = __builtin_elementwise_fma(w1v, v, c1a);                         \
        c2a = __builtin_elementwise_fma(w2v, v, c2a);                         \
        v.x = __uint_as_float((g).y << 16);                                   \
        v.y = __uint_as_float((g).y & 0xFFFF0000u);                           \
        c1b = __builtin_elementwise_fma(w1v, v, c1b);                         \
        c2b = __builtin_elementwise_fma(w2v, v, c2b);                         \
    } while (0)

__global__ __launch_bounds__(256) void k_agg(
    const unsigned short* __restrict__ X0, const unsigned short* __restrict__ X1,
    const int* __restrict__ off0, const int* __restrict__ off1,
    const uint2* __restrict__ rec0, const uint2* __restrict__ rec1,
    unsigned short* __restrict__ A0, unsigned short* __restrict__ A1, int n) {
    const int s = blockIdx.y;
    const unsigned short* X = s ? X1 : X0;
    const int* off = s ? off1 : off0;
    const uint2* rec = s ? rec1 : rec0;
    unsigned short* A = s ? A1 : A0;

    const int gw = (blockIdx.x * 256 + threadIdx.x) >> 6;
    const int lane = threadIdx.x & 63;
    if (gw >= n) return;

    const int e0 = __builtin_amdgcn_readfirstlane(off[gw]);
    const int e1 = __builtin_amdgcn_readfirstlane(off[gw + 1]);
    const uint2* X2 = (const uint2*)X;          // 4 bf16 per lane-chunk

    f32x2 c1a = {0.f, 0.f}, c1b = {0.f, 0.f};
    f32x2 c2a = {0.f, 0.f}, c2b = {0.f, 0.f};

    const uint4* recq = (const uint4*)(rec + e0);   // 1 uint4 = 2 records
    const int nit = (e1 - e0) >> 2;                 // 4 records / iter, >= 1
    #pragma unroll 2
    for (int it = 0; it < nit; ++it) {
        uint4 qa = recq[it * 2];
        uint4 qb = recq[it * 2 + 1];
        unsigned s0 = (unsigned)__builtin_amdgcn_readfirstlane(qa.x);
        unsigned s1 = (unsigned)__builtin_amdgcn_readfirstlane(qa.z);
        unsigned s2 = (unsigned)__builtin_amdgcn_readfirstlane(qb.x);
        unsigned s3 = (unsigned)__builtin_amdgcn_readfirstlane(qb.z);
        uint2 g0 = X2[(size_t)s0 * 64 + lane];
        uint2 g1 = X2[(size_t)s1 * 64 + lane];
        uint2 g2 = X2[(size_t)s2 * 64 + lane];
        uint2 g3 = X2[(size_t)s3 * 64 + lane];
        AGG4(g0, qa.y);
        AGG4(g1, qa.w);
        AGG4(g2, qb.y);
        AGG4(g3, qb.w);
    }

    uint2 o1, o2;
    o1.x = (unsigned)f2b(c1a.x) | ((unsigned)f2b(c1a.y) << 16);
    o1.y = (unsigned)f2b(c1b.x) | ((unsigned)f2b(c1b.y) << 16);
    o2.x = (unsigned)f2b(c2a.x) | ((unsigned)f2b(c2a.y) << 16);
    o2.y = (unsigned)f2b(c2b.x) | ((unsigned)f2b(c2b.y) << 16);
    *(uint2*)(A + (size_t)gw * 512 + lane * 4) = o1;
    *(uint2*)(A + (size_t)gw * 512 + 256 + lane * 4) = o2;
}

// ---------------- bf16 MFMA GEMM kernels ----------------
#define GLL(g, l) \
    __builtin_amdgcn_global_load_lds((__attribute__((address_space(1))) void*)(g), \
                                     (__attribute__((address_space(3))) void*)(l), 16, 0, 0)

// node-transform GEMM: C[M][Nc] = A[M][K] @ B[Nc][K]^T, bf16 out, z selects B/out.
__global__ __launch_bounds__(256) void gemm_bt(
    const unsigned short* __restrict__ A,
    const unsigned short* __restrict__ B0, const unsigned short* __restrict__ B1,
    int M, int K, int Nc,
    unsigned short* __restrict__ outH0, unsigned short* __restrict__ outH1) {
    const unsigned short* B = blockIdx.z ? B1 : B0;
    unsigned short* outH = blockIdx.z ? outH1 : outH0;

    __shared__ __align__(16) unsigned short sA[128 * 32];
    __shared__ __align__(16) unsigned short sB[128 * 32];
    const int tid = threadIdx.x;
    const int lane = tid & 63;
    const int wave = tid >> 6;
    const int bm = blockIdx.x * 128;
    const int bn = blockIdx.y * 128;

    const int r0 = wave * 32 + (lane >> 2);
    const int kcol = (lane & 3) * 8;
    const int ga0 = min(bm + r0, M - 1);
    const int ga1 = min(bm + r0 + 16, M - 1);
    const int gb0 = min(bn + r0, Nc - 1);
    const int gb1 = min(bn + r0 + 16, Nc - 1);
    const unsigned short* pa0 = A + (size_t)ga0 * K + kcol;
    const unsigned short* pa1 = A + (size_t)ga1 * K + kcol;
    const unsigned short* pb0 = B + (size_t)gb0 * K + kcol;
    const unsigned short* pb1 = B + (size_t)gb1 * K + kcol;
    unsigned short* la0 = &sA[wave * 1024];
    unsigned short* la1 = &sA[wave * 1024 + 512];
    unsigned short* lb0 = &sB[wave * 1024];
    unsigned short* lb1 = &sB[wave * 1024 + 512];

    floatx4 acc[4][4];
    #pragma unroll
    for (int i = 0; i < 4; i++)
        #pragma unroll
        for (int j = 0; j < 4; j++) acc[i][j] = (floatx4){0.f, 0.f, 0.f, 0.f};

    const int mbase = (wave & 1) * 64 + (lane & 15);
    const int nbase = (wave >> 1) * 64 + (lane & 15);
    const int koff = (lane >> 4) * 8;

    for (int kk = 0; kk < K; kk += 32) {
        GLL(pa0 + kk, la0);
        GLL(pa1 + kk, la1);
        GLL(pb0 + kk, lb0);
        GLL(pb1 + kk, lb1);
        __syncthreads();
        bf16x8 af[4], bf[4];
        #pragma unroll
        for (int mi = 0; mi < 4; mi++)
            af[mi] = *(const bf16x8*)&sA[(mbase + mi * 16) * 32 + koff];
        #pragma unroll
        for (int ni = 0; ni < 4; ni++)
            bf[ni] = *(const bf16x8*)&sB[(nbase + ni * 16) * 32 + koff];
        #pragma unroll
        for (int mi = 0; mi < 4; mi++)
            #pragma unroll
            for (int ni = 0; ni < 4; ni++)
                acc[mi][ni] = __builtin_amdgcn_mfma_f32_16x16x32_bf16(
                    af[mi], bf[ni], acc[mi][ni], 0, 0, 0);
        __syncthreads();
    }

    const int crow = bm + (wave & 1) * 64 + (lane >> 4) * 4;
    const int ccol = bn + (wave >> 1) * 64 + (lane & 15);
    #pragma unroll
    for (int mi = 0; mi < 4; mi++)
        #pragma unroll
        for (int ni = 0; ni < 4; ni++)
            #pragma unroll
            for (int r = 0; r < 4; r++) {
                int row = crow + mi * 16 + r;
                if (row >= M) continue;
                int col = ccol + ni * 16;
                outH[(size_t)row * Nc + col] = f2b(acc[mi][ni][r]);
            }
}

// dual GEMM: C = 0.5*relu(A0@B0^T) + 0.5*relu(A1@B1^T); out f32 or bf16.
__global__ __launch_bounds__(256) void gemm_dual(
    const unsigned short* __restrict__ A0, const unsigned short* __restrict__ B0,
    const unsigned short* __restrict__ A1, const unsigned short* __restrict__ B1,
    int M, int K, int Nc,
    float* __restrict__ outF, unsigned short* __restrict__ outH, float alpha) {
    __shared__ __align__(16) unsigned short sA[128 * 32];
    __shared__ __align__(16) unsigned short sB[128 * 32];
    const int tid = threadIdx.x;
    const int lane = tid & 63;
    const int wave = tid >> 6;
    const int bm = blockIdx.x * 128;
    const int bn = blockIdx.y * 128;

    const int r0 = wave * 32 + (lane >> 2);
    const int kcol = (lane & 3) * 8;
    const int ga0 = min(bm + r0, M - 1);
    const int ga1 = min(bm + r0 + 16, M - 1);
    const int gb0 = min(bn + r0, Nc - 1);
    const int gb1 = min(bn + r0 + 16, Nc - 1);
    unsigned short* la0 = &sA[wave * 1024];
    unsigned short* la1 = &sA[wave * 1024 + 512];
    unsigned short* lb0 = &sB[wave * 1024];
    unsigned short* lb1 = &sB[wave * 1024 + 512];

    const int mbase = (wave & 1) * 64 + (lane & 15);
    const int nbase = (wave >> 1) * 64 + (lane & 15);
    const int koff = (lane >> 4) * 8;

    floatx4 acc[4][4], res[4][4];

    #pragma unroll
    for (int pass = 0; pass < 2; pass++) {
        const unsigned short* A = pass ? A1 : A0;
        const unsigned short* B = pass ? B1 : B0;
        const unsigned short* pa0 = A + (size_t)ga0 * K + kcol;
        const unsigned short* pa1 = A + (size_t)ga1 * K + kcol;
        const unsigned short* pb0 = B + (size_t)gb0 * K + kcol;
        const unsigned short* pb1 = B + (size_t)gb1 * K + kcol;
        #pragma unroll
        for (int i = 0; i < 4; i++)
            #pragma unroll
            for (int j = 0; j < 4; j++) acc[i][j] = (floatx4){0.f, 0.f, 0.f, 0.f};

        for (int kk = 0; kk < K; kk += 32) {
            GLL(pa0 + kk, la0);
            GLL(pa1 + kk, la1);
            GLL(pb0 + kk, lb0);
            GLL(pb1 + kk, lb1);
            __syncthreads();
            bf16x8 af[4], bf[4];
            #pragma unroll
            for (int mi = 0; mi < 4; mi++)
                af[mi] = *(const bf16x8*)&sA[(mbase + mi * 16) * 32 + koff];
            #pragma unroll
            for (int ni = 0; ni < 4; ni++)
                bf[ni] = *(const bf16x8*)&sB[(nbase + ni * 16) * 32 + koff];
            #pragma unroll
            for (int mi = 0; mi < 4; mi++)
                #pragma unroll
                for (int ni = 0; ni < 4; ni++)
                    acc[mi][ni] = __builtin_amdgcn_mfma_f32_16x16x32_bf16(
                        af[mi], bf[ni], acc[mi][ni], 0, 0, 0);
            __syncthreads();
        }
        if (pass == 0) {
            #pragma unroll
            for (int mi = 0; mi < 4; mi++)
                #pragma unroll
                for (int ni = 0; ni < 4; ni++)
                    #pragma unroll
                    for (int r = 0; r < 4; r++)
                        res[mi][ni][r] = fmaxf(acc[mi][ni][r], 0.0f);
        }
    }

    const int crow = bm + (wave & 1) * 64 + (lane >> 4) * 4;
    const int ccol = bn + (wave >> 1) * 64 + (lane & 15);
    #pragma unroll
    for (int mi = 0; mi < 4; mi++)
        #pragma unroll
        for (int ni = 0; ni < 4; ni++)
            #pragma unroll
            for (int r = 0; r < 4; r++) {
                int row = crow + mi * 16 + r;
                if (row >= M) continue;
                int col = ccol + ni * 16;
                float v = alpha * (res[mi][ni][r] + fmaxf(acc[mi][ni][r], 0.0f));
                size_t idx = (size_t)row * Nc + col;
                if (outF) outF[idx] = v;
                else      outH[idx] = f2b(v);
            }
}

// ---------------- host orchestration ----------------

extern "C" void kernel_launch(void* const* d_in, const int* in_sizes, int n_in,
                              void* d_out, int out_size, void* d_ws, size_t ws_size,
                              hipStream_t stream) {
    const int F = 256;
    const int N = in_sizes[0] / F;
    const int PEd = in_sizes[1] / N;          // 98
    const int E = in_sizes[2] / 2;            // 800000
    const int KC = F + PEd;                   // 354
    const int KP = (KC + 31) & ~31;           // 384

    const float* x   = (const float*)d_in[0];
    const float* pe  = (const float*)d_in[1];
    const int*   ei0 = (const int*)d_in[2];
    const float* ea0 = (const float*)d_in[3];
    const int*   ei1 = (const int*)d_in[4];
    const float* ea1 = (const float*)d_in[5];
    const float* Wn1 = (const float*)d_in[6];
    const float* Wn2 = (const float*)d_in[7];
    const float* W11 = (const float*)d_in[8];
    const float* W12 = (const float*)d_in[9];
    const float* W21 = (const float*)d_in[10];
    const float* W22 = (const float*)d_in[11];
    const float* W31 = (const float*)d_in[12];
    const float* W32 = (const float*)d_in[13];
    const float* W41 = (const float*)d_in[14];
    const float* W42 = (const float*)d_in[15];
    float* out = (float*)d_out;

    char* p = (char*)d_ws;
    auto alloc = [&](size_t b) -> char* {
        char* r = p;
        p += (b + 255) & ~(size_t)255;
        return r;
    };
    int*   cnt0  = (int*)alloc((size_t)N * 4);
    int*   cnt1  = (int*)alloc((size_t)N * 4);
    int*   off0  = (int*)alloc((size_t)(N + 1) * 4);
    int*   off1  = (int*)alloc((size_t)(N + 1) * 4);
    int*   cur0  = (int*)alloc((size_t)N * 4);
    int*   cur1  = (int*)alloc((size_t)N * 4);
    float* dinv0 = (float*)alloc((size_t)N * 4);
    float* dinv1 = (float*)alloc((size_t)N * 4);
    int*   bs0   = (int*)alloc(64 * 4);
    int*   bs1   = (int*)alloc(64 * 4);
    uint2* rec0  = (uint2*)alloc(((size_t)E + 4ull * N) * 8);   // padded CSR
    uint2* rec1  = (uint2*)alloc(((size_t)E + 4ull * N) * 8);
    unsigned short* wn0c = (unsigned short*)alloc((size_t)F * KP * 2);
    unsigned short* wn1c = (unsigned short*)alloc((size_t)F * KP * 2);
    unsigned short* wc0  = (unsigned short*)alloc((size_t)F * 512 * 2);
    unsigned short* wc1  = (unsigned short*)alloc((size_t)F * 512 * 2);
    unsigned short* wc2  = (unsigned short*)alloc((size_t)F * 512 * 2);
    unsigned short* wc3  = (unsigned short*)alloc((size_t)F * 512 * 2);
    unsigned short* xa   = (unsigned short*)alloc((size_t)N * 512 * 2);  // xa|xb
    unsigned short* xb   = xa + (size_t)N * 256;
    unsigned short* h    = (unsigned short*)alloc((size_t)N * F * 2);
    unsigned short* a12  = (unsigned short*)alloc((size_t)N * 512 * 2);
    unsigned short* xc   = a12;                  // dead after node transforms
    unsigned short* a12bL1 = (unsigned short*)d_out;  // N*512 bf16 == out_size f32
    unsigned short* a12bL2 = xa;                 // xa|xb dead after layer-1 agg

    const int B = 256;
    const int gE = (E + B - 1) / B;
    const int gN = (N + B - 1) / B;
    const int gW = (N + 3) / 4;                  // 4 waves (nodes) per block
    const int nb = (N + 1023) / 1024;            // scan blocks
    dim3 gemm_grid((N + 127) / 128, 2);
    dim3 gemm_grid2((N + 127) / 128, 2, 2);

    // 1. fused front: degree atomics + xc conversion + weight conversions
    //    (cnt0|cnt1 are adjacent 256-aligned allocs -> one memset)
    hipMemsetAsync(cnt0, 0, (size_t)((char*)cur0 - (char*)cnt0) - 
                   ((size_t)(N + 1) * 4 + 255 & ~(size_t)255) * 0, stream);
    // simpler: zero cnt0..cnt1 span explicitly
    hipMemsetAsync(cnt0, 0, (size_t)((char*)off0 - (char*)cnt0), stream);
    {
        const int NXC = N * (KP >> 3);
        const int TOTW = 2 * F * KP + 4 * F * 512;
        long long tot = 2ll * E + NXC + TOTW;
        k_front<<<(unsigned)((tot + B - 1) / B), B, 0, stream>>>(
            ei0 + E, ei1 + E, E, cnt0, cnt1, x, pe, xc,
            Wn1, Wn2, W11, W12, W21, W22, W31, W32, W41, W42,
            wn0c, wn1c, wc0, wc1, wc2, wc3, N, F, PEd, KC, KP);
    }

    // 2. scans + CSR build
    k_scanA<<<dim3(nb, 2), 1024, 0, stream>>>(cnt0, cnt1, off0, off1, bs0, bs1, N);
    k_scanB<<<dim3(1, 2), 64, 0, stream>>>(bs0, bs1, nb);
    k_scanC<<<dim3(nb, 2), 1024, 0, stream>>>(bs0, bs1, cnt0, cnt1, off0, off1,
                                              dinv0, dinv1, cur0, cur1, N);
    k_fillpad<<<dim3(gE + gN, 2), B, 0, stream>>>(
        ei0, ea0, ei1, ea1, E, gE * B, cnt0, cnt1, off0, off1,
        dinv0, dinv1, cur0, cur1, rec0, rec1, N);

    // 3. node transforms (both via blockIdx.z) -> xa, xb  [row-major N x 256]
    gemm_bt<<<gemm_grid2, B, 0, stream>>>(xc, wn0c, wn1c, N, KP, F, xa, xb);

    // 4. layer 1: both aggs in one dispatch; then dual GEMM -> h (bf16)
    k_agg<<<dim3(gW, 2), B, 0, stream>>>(xa, xb, off0, off1, rec0, rec1,
                                         a12, a12bL1, N);
    gemm_dual<<<gemm_grid, B, 0, stream>>>(a12, wc0, a12bL1, wc1, N, 512, F,
                                           nullptr, h, 0.5f);

    // 5. layer 2: both aggs in one dispatch; then dual GEMM -> out (f32)
    k_agg<<<dim3(gW, 2), B, 0, stream>>>(h, h, off0, off1, rec0, rec1,
                                         a12, a12bL2, N);
    gemm_dual<<<gemm_grid, B, 0, stream>>>(a12, wc2, a12bL2, wc3, N, 512, F,
                                           out, nullptr, 0.5f);
}